// Round 8
// baseline (9085.315 us; speedup 1.0000x reference)
//
#include <hip/hip_runtime.h>
#include <hip/hip_bf16.h>

// GraphBertEncoder: T=32768 tokens, S=6, D=256, H=8 (hd=32), L=4.
// Round 8: round-4 proven GEMM schedule (depth-2 B prefetch, 4 MFMA chains,
// NO setprio) + round-7 LDS diet (24-row buffers via overlapped M-tiles
// rows 0-15 / 8-23) + launch_bounds(256,3) for 3 blocks/CU. Two-phase
// attention (scores+softmax -> attw; o = a@v), attw overlaid on redbuf.

#define TB 4
#define NROW 24

typedef float f32x4 __attribute__((ext_vector_type(4)));
typedef short bfv8  __attribute__((ext_vector_type(8)));   // 8 bf16 = 4 VGPR

__device__ __forceinline__ float bf2f(__hip_bfloat16 v) { return __bfloat162float(v); }
__device__ __forceinline__ __hip_bfloat16 f2bf(float v) { return __float2bfloat16(v); }
__device__ __forceinline__ float bfs2f(short s) { return __uint_as_float(((unsigned)(unsigned short)s) << 16); }
// swizzled byte offset into a [24][512B] bf16 tile
__device__ __forceinline__ int swz(int row, int cb) { return row*512 + (cb ^ ((row & 7) << 4)); }
__device__ __forceinline__ float gelu_f(float v) { return 0.5f*v*(1.f + erff(v*0.70710678118654752f)); }
__device__ __forceinline__ float unpk(unsigned p, int hi) {
  return __uint_as_float(hi ? (p & 0xffff0000u) : (p << 16));
}

// ws fragment-layout offsets (bf16 elements)
#define OWQ 0u
#define OWO 786432u
#define OW1 1048576u
#define OW2 2097152u
#define WS_ELEMS 3145728u   // *2B = 6291456 bytes

// LDS layout (bytes): 4 regions of 12288 + attw/redbuf overlay
#define O_R1  12288
#define O_R2  24576
#define O_R3  36864
#define O_ATT 49152   // attw (4608B) overlaid with redbuf (768B) - disjoint phases
#define SMEM_SZ 53760 // x3 = 161280 <= 163840 -> 3 blocks/CU

// ---------------------------------------------------------------------------
// prep: fp32 weights -> bf16 B-fragment-linear in ws (unchanged).
__global__ __launch_bounds__(256) void gb_prep_kernel(
    const float* __restrict__ Wqkv, const float* __restrict__ Wo,
    const float* __restrict__ W1,   const float* __restrict__ W2,
    __hip_bfloat16* __restrict__ ws)
{
  int fg   = blockIdx.x * 4 + (threadIdx.x >> 6);   // 0..6143
  int lane = threadIdx.x & 63;
  int layer = fg / 1536, r = fg % 1536;
  const float* src; int K, N, fl; unsigned dstbase;
  if (r < 384)       { src = Wqkv + layer*196608; K = 256;  N = 768;  fl = r;       dstbase = OWQ + layer*196608u; }
  else if (r < 512)  { src = Wo   + layer*65536;  K = 256;  N = 256;  fl = r - 384; dstbase = OWO + layer*65536u;  }
  else if (r < 1024) { src = W1   + layer*262144; K = 256;  N = 1024; fl = r - 512; dstbase = OW1 + layer*262144u; }
  else               { src = W2   + layer*262144; K = 1024; N = 256;  fl = r - 1024;dstbase = OW2 + layer*262144u; }
  int nk = K >> 5;
  int nt = fl / nk, ks = fl % nk;
  int n  = nt*16 + (lane & 15);
  int k0 = ks*32 + (lane >> 4)*8;
  __align__(16) __hip_bfloat16 tmp[8];
  #pragma unroll
  for (int j = 0; j < 8; ++j) tmp[j] = f2bf(src[(size_t)(k0 + j)*N + n]);
  *(uint4*)(ws + dstbase + (unsigned)fl*512u + lane*8) = *(const uint4*)tmp;
}

// ---------------------------------------------------------------------------
__device__ __forceinline__ void preload8(const __hip_bfloat16* __restrict__ p, bfv8 (&b)[8]) {
  #pragma unroll
  for (int k = 0; k < 8; ++k) b[k] = *(const bfv8*)(p + k*512);
}

// one-pass LayerNorm over 256 columns for 24 rows (thread owns column tid).
__device__ __forceinline__ void ln24_norm(float* z, float* redbuf, float g, float b, int tid) {
  const int lane = tid & 63, wid = tid >> 6;
  float s1[NROW], s2[NROW];
  #pragma unroll
  for (int r = 0; r < NROW; ++r) { float v = z[r]; s1[r] = v; s2[r] = v*v; }
  #pragma unroll
  for (int off = 32; off; off >>= 1) {
    #pragma unroll
    for (int r = 0; r < NROW; ++r) {
      s1[r] += __shfl_down(s1[r], off, 64);
      s2[r] += __shfl_down(s2[r], off, 64);
    }
  }
  if (lane == 0) {
    #pragma unroll
    for (int r = 0; r < NROW; ++r) { redbuf[wid*48 + r] = s1[r]; redbuf[wid*48 + 24 + r] = s2[r]; }
  }
  __syncthreads();
  #pragma unroll
  for (int r = 0; r < NROW; ++r) {
    float S1 = redbuf[r] + redbuf[48+r] + redbuf[96+r] + redbuf[144+r];
    float S2 = redbuf[24+r] + redbuf[72+r] + redbuf[120+r] + redbuf[168+r];
    float m  = S1 * (1.0f/256.0f);
    float var = S2 * (1.0f/256.0f) - m*m;
    float iv = rsqrtf(var + 1e-5f);
    z[r] = (z[r] - m) * iv * g + b;
  }
  __syncthreads();
}

// ---------------------------------------------------------------------------
// GEMM section (round-4 proven): NTI n-tiles (nt = wid + 4*i), K=256 per tile,
// double-buffered B prefetch, 4 independent MFMA chains. NO setprio (hurts
// lockstep: rounds 6/7 doubled L2-miss FETCH with it).
template<int NTI, int NKTOT, class Epi>
__device__ __forceinline__ void gemm_sec(const __hip_bfloat16* __restrict__ p,
                                         const bfv8 (&a0)[8], const bfv8 (&a1)[8],
                                         Epi epi)
{
  const unsigned ST = 4u*(unsigned)NKTOT*512u;
  bfv8 bA[8], bB[8];
  preload8(p, bA);
  #pragma unroll
  for (int i = 0; i < NTI; i += 2) {
    preload8(p + (unsigned)(i+1)*ST, bB);
    {
      f32x4 c0a = {0,0,0,0}, c0b = {0,0,0,0}, c1a = {0,0,0,0}, c1b = {0,0,0,0};
      #pragma unroll
      for (int k = 0; k < 8; k += 2) {
        c0a = __builtin_amdgcn_mfma_f32_16x16x32_bf16(a0[k],   bA[k],   c0a, 0,0,0);
        c1a = __builtin_amdgcn_mfma_f32_16x16x32_bf16(a1[k],   bA[k],   c1a, 0,0,0);
        c0b = __builtin_amdgcn_mfma_f32_16x16x32_bf16(a0[k+1], bA[k+1], c0b, 0,0,0);
        c1b = __builtin_amdgcn_mfma_f32_16x16x32_bf16(a1[k+1], bA[k+1], c1b, 0,0,0);
      }
      epi(i, c0a + c0b, c1a + c1b);
    }
    if (i + 2 < NTI) preload8(p + (unsigned)(i+2)*ST, bA);
    {
      f32x4 c0a = {0,0,0,0}, c0b = {0,0,0,0}, c1a = {0,0,0,0}, c1b = {0,0,0,0};
      #pragma unroll
      for (int k = 0; k < 8; k += 2) {
        c0a = __builtin_amdgcn_mfma_f32_16x16x32_bf16(a0[k],   bB[k],   c0a, 0,0,0);
        c1a = __builtin_amdgcn_mfma_f32_16x16x32_bf16(a1[k],   bB[k],   c1a, 0,0,0);
        c0b = __builtin_amdgcn_mfma_f32_16x16x32_bf16(a0[k+1], bB[k+1], c0b, 0,0,0);
        c1b = __builtin_amdgcn_mfma_f32_16x16x32_bf16(a1[k+1], bB[k+1], c1b, 0,0,0);
      }
      epi(i+1, c0a + c0b, c1a + c1b);
    }
  }
}

// ---------------------------------------------------------------------------
__global__ __launch_bounds__(256, 3) void gb_mfma_kernel(
    const float* __restrict__ x,
    const float* __restrict__ W_raw, const float* __restrict__ b_raw,
    const float* __restrict__ wl_emb, const float* __restrict__ pos_emb,
    const float* __restrict__ hop_emb,
    const float* __restrict__ ln_g, const float* __restrict__ ln_b,
    const float* __restrict__ bqkv, const float* __restrict__ bo,
    const float* __restrict__ n1g,  const float* __restrict__ n1b,
    const float* __restrict__ b1,   const float* __restrict__ b2,
    const float* __restrict__ n2g,  const float* __restrict__ n2b,
    const float* __restrict__ W_res, const float* __restrict__ b_res,
    const __hip_bfloat16* __restrict__ wf,
    float* __restrict__ out)
{
  __shared__ __align__(16) char smem[SMEM_SZ];
  char* hsb = smem;                 // [24][512B] swz bf16 (h)
  char* uQ  = smem + O_R1;          // xbuf(embed) | Q | o
  char* uK  = smem + O_R2;          // K | fbuf-lo | gelu0
  char* uV  = smem + O_R3;          // V | fbuf-hi | gelu1
  float (*attw)[24][6] = (float (*)[24][6])(smem + O_ATT);
  float* redbuf = (float*)(smem + O_ATT);               // overlay (disjoint phases)
  float (*fbuf)[256] = (float (*)[256])(smem + O_R2);   // 24x256 fp32 = R2+R3
  float (*xbuf)[128] = (float (*)[128])(smem + O_R1);   // 24x128 fp32 = R1

  const int tid  = threadIdx.x;
  const int bt   = blockIdx.x;
  const int lane = tid & 63, wid = tid >> 6;
  const int l15  = lane & 15, l4 = lane >> 4;

  // ---------------- Embedding: stage sub_x rows (fp32, idx mapping) --------
  for (int idx = tid; idx < TB*6*128; idx += 256) {
    int tt = idx / 768, rem = idx % 768;
    int s = rem >> 7, f = rem & 127;
    int t = bt*TB + tt, g = t >> 7, i = t & 127;
    int node;
    if (s < 2) node = i;
    else { int j = s - 2; node = (j < i) ? j : (j + 1); }
    xbuf[tt*6+s][f] = x[(g*128 + node)*128 + f];
  }
  __syncthreads();

  float z[NROW];
  {
    #pragma unroll
    for (int r = 0; r < NROW; ++r) z[r] = 0.f;
    #pragma unroll 2
    for (int f4 = 0; f4 < 32; ++f4) {
      float w0 = W_raw[(f4*4+0)*256 + tid];
      float w1 = W_raw[(f4*4+1)*256 + tid];
      float w2 = W_raw[(f4*4+2)*256 + tid];
      float w3 = W_raw[(f4*4+3)*256 + tid];
      #pragma unroll
      for (int r = 0; r < NROW; ++r) {
        float4 xv = *(const float4*)(&xbuf[r][f4*4]);
        z[r] += xv.x*w0 + xv.y*w1 + xv.z*w2 + xv.w*w3;
      }
    }
    float br  = b_raw[tid];
    float wl  = wl_emb[tid];
    float hp0 = hop_emb[5*256 + tid];
    float hp1 = hop_emb[511*256 + tid];
    float p[6];
    #pragma unroll
    for (int s = 0; s < 6; ++s) p[s] = pos_emb[s*256 + tid];
    #pragma unroll
    for (int r = 0; r < NROW; ++r) {
      int s = r % 6;
      z[r] += br + p[s] + wl + ((s < 2) ? hp0 : hp1);
    }
  }
  ln24_norm(z, redbuf, ln_g[tid], ln_b[tid], tid);
  #pragma unroll
  for (int r = 0; r < NROW; ++r)
    *(__hip_bfloat16*)(hsb + swz(r, tid*2)) = f2bf(z[r]);

  // ---------------- res (bt<64 only), packed bf16 pairs --------------------
  unsigned resp[12];
  #pragma unroll
  for (int k = 0; k < 12; ++k) resp[k] = 0u;
  if (bt < 64) {
    __syncthreads();   // embed xbuf reads done (uniform branch)
    for (int idx = tid; idx < TB*6*128; idx += 256) {
      int tt = idx / 768, rem = idx % 768;
      int s = rem >> 7, f = rem & 127;
      int t = bt*TB + tt;
      xbuf[tt*6+s][f] = x[(t*128 + s)*128 + f];
    }
    __syncthreads();
    float resv[NROW];
    float brr = b_res[tid];
    #pragma unroll
    for (int r = 0; r < NROW; ++r) resv[r] = brr;
    #pragma unroll 2
    for (int f4 = 0; f4 < 32; ++f4) {
      float w0 = W_res[(f4*4+0)*256 + tid];
      float w1 = W_res[(f4*4+1)*256 + tid];
      float w2 = W_res[(f4*4+2)*256 + tid];
      float w3 = W_res[(f4*4+3)*256 + tid];
      #pragma unroll
      for (int r = 0; r < NROW; ++r) {
        float4 xv = *(const float4*)(&xbuf[r][f4*4]);
        resv[r] += xv.x*w0 + xv.y*w1 + xv.z*w2 + xv.w*w3;
      }
    }
    #pragma unroll
    for (int k = 0; k < 12; ++k) {
      unsigned lo = __float_as_uint(resv[2*k])   >> 16;
      unsigned hi = __float_as_uint(resv[2*k+1]) & 0xffff0000u;
      resp[k] = hi | lo;
    }
  }

  // ---------------- layers ----------------
  #pragma unroll 1
  for (int l = 0; l < 4; ++l) {
    const __hip_bfloat16* WQf = wf + OWQ + (unsigned)l*196608u;
    const __hip_bfloat16* WOf = wf + OWO + (unsigned)l*65536u;
    const __hip_bfloat16* W1f = wf + OW1 + (unsigned)l*262144u;
    const __hip_bfloat16* W2f = wf + OW2 + (unsigned)l*262144u;

    float n1gv = n1g[l*256 + tid], n1bv = n1b[l*256 + tid];
    float n2gv = n2g[l*256 + tid], n2bv = n2b[l*256 + tid];
    float bov  = bo[l*256 + tid],  b2v  = b2[l*256 + tid];

    float bb[12];
    #pragma unroll
    for (int i = 0; i < 12; ++i) bb[i] = bqkv[l*768 + (wid + i*4)*16 + l15];

    __syncthreads();   // hsb visible; R1-R3 free

    // ---- QKV (N=768, K=256): epi routes n-tile groups to Q/K/V buffers ----
    {
      bfv8 a0[8], a1[8];
      #pragma unroll
      for (int ks = 0; ks < 8; ++ks) {
        a0[ks] = *(const bfv8*)(hsb + swz(l15,     ks*64 + l4*16));   // rows 0-15
        a1[ks] = *(const bfv8*)(hsb + swz(8 + l15, ks*64 + l4*16));   // rows 8-23
      }
      gemm_sec<12, 8>(WQf + (unsigned)wid*8u*512u + lane*8, a0, a1,
        [&](int i, f32x4 c0, f32x4 c1) {
          char* qb = smem + O_R1 + (i >> 2)*12288;     // Q / K / V
          int col = (wid + (i & 3)*4)*16 + l15;
          float bbv = bb[i];
          #pragma unroll
          for (int j = 0; j < 4; ++j)
            *(__hip_bfloat16*)(qb + swz(l4*4 + j, col*2)) = f2bf(c0[j] + bbv);
          if (l4 >= 2) {
            #pragma unroll
            for (int j = 0; j < 4; ++j)
              *(__hip_bfloat16*)(qb + swz(8 + l4*4 + j, col*2)) = f2bf(c1[j] + bbv);
          }
        });
    }
    __syncthreads();

    // ---- attention phase 1: scores + softmax -> attw (threads 0..191) ----
    if (tid < 192) {
      int hh = tid / 24, r = tid % 24;
      int tr = (r / 6) * 6;
      int cb = hh * 64;                 // byte col base
      bfv8 qv[4];
      #pragma unroll
      for (int p4 = 0; p4 < 4; ++p4)
        qv[p4] = *(const bfv8*)(uQ + swz(r, cb + p4*16));
      float a[6]; float mx = -1e30f;
      #pragma unroll
      for (int sp = 0; sp < 6; ++sp) {
        float s = 0.f;
        #pragma unroll
        for (int p4 = 0; p4 < 4; ++p4) {
          bfv8 kv = *(const bfv8*)(uK + swz(tr + sp, cb + p4*16));
          #pragma unroll
          for (int j = 0; j < 8; ++j) s += bfs2f(qv[p4][j]) * bfs2f(kv[j]);
        }
        a[sp] = s * 0.17677669529663687f;   // 1/sqrt(32)
        mx = fmaxf(mx, a[sp]);
      }
      float sum = 0.f;
      #pragma unroll
      for (int sp = 0; sp < 6; ++sp) { a[sp] = __expf(a[sp] - mx); sum += a[sp]; }
      float inv = 1.f / sum;
      #pragma unroll
      for (int sp = 0; sp < 6; ++sp) attw[hh][r][sp] = a[sp] * inv;
    }
    __syncthreads();   // attw visible; Q dead

    // ---- attention phase 2: o = a @ v -> R1 over Q (thread (hh,c)) ----
    {
      int hh = tid >> 5, c = tid & 31;
      int col2 = (hh*32 + c)*2;
      #pragma unroll
      for (int tt = 0; tt < 4; ++tt) {
        float vv[6];
        #pragma unroll
        for (int sp = 0; sp < 6; ++sp)
          vv[sp] = bf2f(*(const __hip_bfloat16*)(uV + swz(tt*6 + sp, col2)));
        #pragma unroll
        for (int q = 0; q < 6; ++q) {
          float o = 0.f;
          #pragma unroll
          for (int sp = 0; sp < 6; ++sp) o += attw[hh][tt*6 + q][sp] * vv[sp];
          *(__hip_bfloat16*)(uQ + swz(tt*6 + q, col2)) = f2bf(o);
        }
      }
    }
    __syncthreads();   // o visible; K/V dead

    // ---- attn = o @ Wo -> fbuf fp32 (R2+R3) ----
    {
      bfv8 a0[8], a1[8];
      #pragma unroll
      for (int ks = 0; ks < 8; ++ks) {
        a0[ks] = *(const bfv8*)(uQ + swz(l15,     ks*64 + l4*16));
        a1[ks] = *(const bfv8*)(uQ + swz(8 + l15, ks*64 + l4*16));
      }
      gemm_sec<4, 8>(WOf + (unsigned)wid*8u*512u + lane*8, a0, a1,
        [&](int i, f32x4 c0, f32x4 c1) {
          int col = (wid + i*4)*16 + l15;
          #pragma unroll
          for (int j = 0; j < 4; ++j) fbuf[l4*4 + j][col] = c0[j];
          if (l4 >= 2) {
            #pragma unroll
            for (int j = 0; j < 4; ++j) fbuf[8 + l4*4 + j][col] = c1[j];
          }
        });
    }
    __syncthreads();   // fbuf visible

    // ---- z = h + attn + res ; LN1 ; -> hsb ----
    #pragma unroll
    for (int r = 0; r < NROW; ++r)
      z[r] += unpk(resp[r >> 1], r & 1) + fbuf[r][tid] + bov;
    ln24_norm(z, redbuf, n1gv, n1bv, tid);
    #pragma unroll
    for (int r = 0; r < NROW; ++r)
      *(__hip_bfloat16*)(hsb + swz(r, tid*2)) = f2bf(z[r]);
    __syncthreads();   // hsb visible; fbuf consumed -> R2/R3 free for gelu

    // ---- FFN: 4 hidden chunks; gelu -> dbuf (R2/R3); W2 accumulates in regs
    {
      bfv8 ah0[8], ah1[8];
      #pragma unroll
      for (int ks = 0; ks < 8; ++ks) {
        ah0[ks] = *(const bfv8*)(hsb + swz(l15,     ks*64 + l4*16));
        ah1[ks] = *(const bfv8*)(hsb + swz(8 + l15, ks*64 + l4*16));
      }
      f32x4 facc[8];
      #pragma unroll
      for (int k = 0; k < 8; ++k) facc[k] = (f32x4){0.f,0.f,0.f,0.f};

      #pragma unroll 1
      for (int ch = 0; ch < 4; ++ch) {
        char* gb = smem + O_R2 + (ch & 1)*12288;
        float bb1[4];
        #pragma unroll
        for (int i = 0; i < 4; ++i) bb1[i] = b1[l*1024 + ch*256 + (wid + i*4)*16 + l15];

        gemm_sec<4, 8>(W1f + (unsigned)(ch*128 + wid*8)*512u + lane*8, ah0, ah1,
          [&](int i, f32x4 c0, f32x4 c1) {
            int col2 = ((wid + i*4)*16 + l15)*2;
            #pragma unroll
            for (int j = 0; j < 4; ++j)
              *(__hip_bfloat16*)(gb + swz(l4*4 + j, col2)) = f2bf(gelu_f(c0[j] + bb1[i]));
            if (l4 >= 2) {
              #pragma unroll
              for (int j = 0; j < 4; ++j)
                *(__hip_bfloat16*)(gb + swz(8 + l4*4 + j, col2)) = f2bf(gelu_f(c1[j] + bb1[i]));
            }
          });
        __syncthreads();   // gelu chunk visible

        bfv8 g0[8], g1[8];
        #pragma unroll
        for (int ks = 0; ks < 8; ++ks) {
          g0[ks] = *(const bfv8*)(gb + swz(l15,     ks*64 + l4*16));
          g1[ks] = *(const bfv8*)(gb + swz(8 + l15, ks*64 + l4*16));
        }
        gemm_sec<4, 32>(W2f + (unsigned)(wid*32 + ch*8)*512u + lane*8, g0, g1,
          [&](int i, f32x4 c0, f32x4 c1) {
            facc[2*i]   += c0;
            facc[2*i+1] += c1;
          });
      }
      __syncthreads();   // last gelu reads done -> R2/R3 free for fbuf
      #pragma unroll
      for (int i = 0; i < 4; ++i) {
        int col = (wid + i*4)*16 + l15;
        #pragma unroll
        for (int j = 0; j < 4; ++j) fbuf[l4*4 + j][col] = facc[2*i][j];
        if (l4 >= 2) {
          #pragma unroll
          for (int j = 0; j < 4; ++j) fbuf[8 + l4*4 + j][col] = facc[2*i+1][j];
        }
      }
    }
    __syncthreads();   // fbuf visible

    // ---- z = h1 + ff + res ; LN2 ; -> hsb ----
    #pragma unroll
    for (int r = 0; r < NROW; ++r)
      z[r] += unpk(resp[r >> 1], r & 1) + fbuf[r][tid] + b2v;
    ln24_norm(z, redbuf, n2gv, n2bv, tid);
    #pragma unroll
    for (int r = 0; r < NROW; ++r)
      *(__hip_bfloat16*)(hsb + swz(r, tid*2)) = f2bf(z[r]);
  }

  // ---------------- output: h[:,0] ----------------
  #pragma unroll
  for (int tt = 0; tt < TB; ++tt)
    out[(bt*TB + tt)*256 + tid] = z[tt*6];
}

// ---------------------------------------------------------------------------
// Fallback (pure-VALU, round-2 proven) if ws too small for weight staging.
__global__ __launch_bounds__(256, 2) void gb_fused_fallback(
    const float* __restrict__ x,
    const float* __restrict__ W_raw, const float* __restrict__ b_raw,
    const float* __restrict__ wl_emb, const float* __restrict__ pos_emb,
    const float* __restrict__ hop_emb,
    const float* __restrict__ ln_g, const float* __restrict__ ln_b,
    const float* __restrict__ Wqkv, const float* __restrict__ bqkv,
    const float* __restrict__ Wo,   const float* __restrict__ bo,
    const float* __restrict__ n1g,  const float* __restrict__ n1b,
    const float* __restrict__ W1,   const float* __restrict__ b1,
    const float* __restrict__ W2,   const float* __restrict__ b2,
    const float* __restrict__ n2g,  const float* __restrict__ n2b,
    const float* __restrict__ W_res, const float* __restrict__ b_res,
    float* __restrict__ out)
{
  __shared__ float hs[NROW][256];
  __shared__ __align__(16) char bufraw[NROW*768*2];
  __shared__ float attw[8][NROW][8];
  __shared__ float redbuf[192];

  __hip_bfloat16 (*qkvs)[768] = (__hip_bfloat16 (*)[768])bufraw;
  float (*fbuf)[256] = (float (*)[256])bufraw;
  float (*xbuf)[128] = (float (*)[128])bufraw;

  const int tid = threadIdx.x;
  const int bt  = blockIdx.x;

  for (int idx = tid; idx < TB*6*128; idx += 256) {
    int tt = idx / 768, rem = idx % 768;
    int s = rem >> 7, f = rem & 127;
    int t = bt*TB + tt, g = t >> 7, i = t & 127;
    int node;
    if (s < 2) node = i;
    else { int j = s - 2; node = (j < i) ? j : (j + 1); }
    xbuf[tt*6+s][f] = x[(g*128 + node)*128 + f];
  }
  __syncthreads();

  float z[NROW];
  {
    #pragma unroll
    for (int r = 0; r < NROW; ++r) z[r] = 0.f;
    #pragma unroll 4
    for (int f = 0; f < 128; ++f) {
      float w = W_raw[f*256 + tid];
      #pragma unroll
      for (int r = 0; r < NROW; ++r) z[r] += xbuf[r][f] * w;
    }
    float br  = b_raw[tid];
    float wl  = wl_emb[tid];
    float hp0 = hop_emb[5*256 + tid];
    float hp1 = hop_emb[511*256 + tid];
    float p[6];
    #pragma unroll
    for (int s = 0; s < 6; ++s) p[s] = pos_emb[s*256 + tid];
    #pragma unroll
    for (int r = 0; r < NROW; ++r) {
      int s = r % 6;
      z[r] += br + p[s] + wl + ((s < 2) ? hp0 : hp1);
    }
  }
  ln24_norm(z, redbuf, ln_g[tid], ln_b[tid], tid);
  #pragma unroll
  for (int r = 0; r < NROW; ++r) hs[r][tid] = z[r];

  float resv[NROW];
  #pragma unroll
  for (int r = 0; r < NROW; ++r) resv[r] = 0.f;
  if (bt < 64) {
    __syncthreads();
    for (int idx = tid; idx < TB*6*128; idx += 256) {
      int tt = idx / 768, rem = idx % 768;
      int s = rem >> 7, f = rem & 127;
      int t = bt*TB + tt;
      xbuf[tt*6+s][f] = x[(t*128 + s)*128 + f];
    }
    __syncthreads();
    #pragma unroll 4
    for (int f = 0; f < 128; ++f) {
      float w = W_res[f*256 + tid];
      #pragma unroll
      for (int r = 0; r < NROW; ++r) resv[r] += xbuf[r][f] * w;
    }
    float brr = b_res[tid];
    #pragma unroll
    for (int r = 0; r < NROW; ++r) resv[r] += brr;
  }

  for (int l = 0; l < 4; ++l) {
    const float* Wqkv_l = Wqkv + l*196608;
    const float* bqkv_l = bqkv + l*768;
    const float* Wo_l   = Wo   + l*65536;
    const float* bo_l   = bo   + l*256;
    const float* W1_l   = W1   + l*262144;
    const float* b1_l   = b1   + l*1024;
    const float* W2_l   = W2   + l*262144;
    const float* b2_l   = b2   + l*256;

    __syncthreads();

    for (int cg = 0; cg < 3; ++cg) {
      int col = cg*256 + tid;
      float acc[NROW];
      #pragma unroll
      for (int r = 0; r < NROW; ++r) acc[r] = 0.f;
      #pragma unroll 4
      for (int kk = 0; kk < 256; ++kk) {
        float w = Wqkv_l[kk*768 + col];
        #pragma unroll
        for (int r = 0; r < NROW; ++r) acc[r] += hs[r][kk] * w;
      }
      float bbv = bqkv_l[col];
      #pragma unroll
      for (int r = 0; r < NROW; ++r) qkvs[r][col] = f2bf(acc[r] + bbv);
    }
    __syncthreads();

    #pragma unroll 1
    for (int it = 0; it < 5; ++it) {
      int idx = it*256 + tid;
      if (idx < 1152) {
        int hh = idx / 144, rem = idx % 144;
        int r = rem / 6, sp = rem % 6;
        int tt6 = (r / 6) * 6;
        float sc = 0.f;
        #pragma unroll
        for (int c = 0; c < 32; ++c)
          sc += bf2f(qkvs[r][hh*32 + c]) * bf2f(qkvs[tt6 + sp][256 + hh*32 + c]);
        attw[hh][r][sp] = sc * 0.17677669529663687f;
      }
    }
    __syncthreads();

    if (tid < 192) {
      int hh = tid / 24, r = tid % 24;
      float mx = attw[hh][r][0];
      #pragma unroll
      for (int sp = 1; sp < 6; ++sp) mx = fmaxf(mx, attw[hh][r][sp]);
      float e[6], sum = 0.f;
      #pragma unroll
      for (int sp = 0; sp < 6; ++sp) { e[sp] = expf(attw[hh][r][sp] - mx); sum += e[sp]; }
      float inv = 1.f / sum;
      #pragma unroll
      for (int sp = 0; sp < 6; ++sp) attw[hh][r][sp] = e[sp] * inv;
    }
    __syncthreads();

    float oreg[NROW];
    {
      int hh = tid >> 5, c = tid & 31;
      #pragma unroll
      for (int r = 0; r < NROW; ++r) {
        int tt6 = (r / 6) * 6;
        float o = 0.f;
        #pragma unroll
        for (int sp = 0; sp < 6; ++sp)
          o += attw[hh][r][sp] * bf2f(qkvs[tt6 + sp][512 + hh*32 + c]);
        oreg[r] = o;
      }
    }
    __syncthreads();
    #pragma unroll
    for (int r = 0; r < NROW; ++r) fbuf[r][tid] = oreg[r];
    __syncthreads();

    {
      float bod = bo_l[tid];
      float zz[NROW];
      #pragma unroll
      for (int r = 0; r < NROW; ++r) zz[r] = bod;
      #pragma unroll 4
      for (int kk = 0; kk < 256; ++kk) {
        float w = Wo_l[kk*256 + tid];
        #pragma unroll
        for (int r = 0; r < NROW; ++r) zz[r] += fbuf[r][kk] * w;
      }
      #pragma unroll
      for (int r = 0; r < NROW; ++r) z[r] += zz[r] + resv[r];
    }
    ln24_norm(z, redbuf, n1g[l*256 + tid], n1b[l*256 + tid], tid);
    #pragma unroll
    for (int r = 0; r < NROW; ++r) hs[r][tid] = z[r];
    __syncthreads();

    float ff[NROW];
    {
      float b2d = b2_l[tid];
      #pragma unroll
      for (int r = 0; r < NROW; ++r) ff[r] = b2d;
    }
    for (int ch = 0; ch < 4; ++ch) {
      int j = ch*256 + tid;
      float gvv[NROW];
      float b1j = b1_l[j];
      #pragma unroll
      for (int r = 0; r < NROW; ++r) gvv[r] = b1j;
      #pragma unroll 4
      for (int kk = 0; kk < 256; ++kk) {
        float w = W1_l[kk*1024 + j];
        #pragma unroll
        for (int r = 0; r < NROW; ++r) gvv[r] += hs[r][kk] * w;
      }
      __syncthreads();
      #pragma unroll
      for (int r = 0; r < NROW; ++r) fbuf[r][tid] = gelu_f(gvv[r]);
      __syncthreads();
      #pragma unroll 4
      for (int kk = 0; kk < 256; ++kk) {
        float w = W2_l[(ch*256 + kk)*256 + tid];
        #pragma unroll
        for (int r = 0; r < NROW; ++r) ff[r] += fbuf[r][kk] * w;
      }
    }
    #pragma unroll
    for (int r = 0; r < NROW; ++r) z[r] += ff[r] + resv[r];
    ln24_norm(z, redbuf, n2g[l*256 + tid], n2b[l*256 + tid], tid);
    #pragma unroll
    for (int r = 0; r < NROW; ++r) hs[r][tid] = z[r];
  }

  __syncthreads();
  #pragma unroll
  for (int tt = 0; tt < TB; ++tt)
    out[(bt*TB + tt)*256 + tid] = hs[tt*6][tid];
}

extern "C" void kernel_launch(void* const* d_in, const int* in_sizes, int n_in,
                              void* d_out, int out_size, void* d_ws, size_t ws_size,
                              hipStream_t stream) {
  (void)in_sizes; (void)n_in; (void)out_size;
  const float* x      = (const float*)d_in[0];
  const float* W_raw  = (const float*)d_in[1];
  const float* b_raw  = (const float*)d_in[2];
  const float* wl_emb = (const float*)d_in[3];
  const float* pos_emb= (const float*)d_in[4];
  const float* hop_emb= (const float*)d_in[5];
  const float* ln_g   = (const float*)d_in[6];
  const float* ln_b   = (const float*)d_in[7];
  const float* Wqkv   = (const float*)d_in[8];
  const float* bqkv   = (const float*)d_in[9];
  const float* Wo     = (const float*)d_in[10];
  const float* bo     = (const float*)d_in[11];
  const float* n1g    = (const float*)d_in[12];
  const float* n1b    = (const float*)d_in[13];
  const float* W1     = (const float*)d_in[14];
  const float* b1     = (const float*)d_in[15];
  const float* W2     = (const float*)d_in[16];
  const float* b2     = (const float*)d_in[17];
  const float* n2g    = (const float*)d_in[18];
  const float* n2b    = (const float*)d_in[19];
  const float* W_res  = (const float*)d_in[20];
  const float* b_res  = (const float*)d_in[21];

  if (ws_size >= (size_t)WS_ELEMS * 2) {
    __hip_bfloat16* wsb = (__hip_bfloat16*)d_ws;
    gb_prep_kernel<<<1536, 256, 0, stream>>>(Wqkv, Wo, W1, W2, wsb);
    gb_mfma_kernel<<<8192, 256, 0, stream>>>(
        x, W_raw, b_raw, wl_emb, pos_emb, hop_emb, ln_g, ln_b,
        bqkv, bo, n1g, n1b, b1, b2, n2g, n2b, W_res, b_res,
        wsb, (float*)d_out);
  } else {
    gb_fused_fallback<<<8192, 256, 0, stream>>>(
        x, W_raw, b_raw, wl_emb, pos_emb, hop_emb, ln_g, ln_b,
        Wqkv, bqkv, Wo, bo, n1g, n1b, W1, b1, W2, b2, n2g, n2b,
        W_res, b_res, (float*)d_out);
  }
}

// Round 9
// 8881.592 us; speedup vs baseline: 1.0229x; 1.0229x over previous
//
#include <hip/hip_runtime.h>
#include <hip/hip_bf16.h>

// GraphBertEncoder: T=32768 tokens, S=6, D=256, H=8 (hd=32), L=4.
// Round 9: TB=8 restructure. 512 threads (8 waves), NROW=48 = 3 clean 16-row
// M-tiles per wave (no overlap waste), 1 block/CU (LDS 106.5KB), 256-VGPR
// budget via launch_bounds(512,2). Depth-2 B prefetch, 6 MFMA chains, no
// setprio. Weight stream halves (4096 blocks). Per-thread row state stays 24
// (half = tid>>8 owns rows half*24..+23 for LN/residual phases).

#define TBK 8
#define NROW 48

typedef float f32x4 __attribute__((ext_vector_type(4)));
typedef short bfv8  __attribute__((ext_vector_type(8)));   // 8 bf16 = 4 VGPR

__device__ __forceinline__ float bf2f(__hip_bfloat16 v) { return __bfloat162float(v); }
__device__ __forceinline__ __hip_bfloat16 f2bf(float v) { return __float2bfloat16(v); }
__device__ __forceinline__ float bfs2f(short s) { return __uint_as_float(((unsigned)(unsigned short)s) << 16); }
// swizzled byte offset into a [rows][512B] bf16 tile
__device__ __forceinline__ int swz(int row, int cb) { return row*512 + (cb ^ ((row & 7) << 4)); }
__device__ __forceinline__ float gelu_f(float v) { return 0.5f*v*(1.f + erff(v*0.70710678118654752f)); }
__device__ __forceinline__ float unpk(unsigned p, int hi) {
  return __uint_as_float(hi ? (p & 0xffff0000u) : (p << 16));
}

// ws fragment-layout offsets (bf16 elements)
#define OWQ 0u
#define OWO 786432u
#define OW1 1048576u
#define OW2 2097152u
#define WS_ELEMS 3145728u   // *2B = 6291456 bytes

// LDS layout (bytes)
#define O_R1  24576     // Q | xbuf | o
#define O_R2  49152     // K | fbuf-lo | gelu0
#define O_R3  73728     // V | fbuf-hi | gelu1
#define O_ATT 98304     // attw 8*48*6*4 = 9216
#define O_RED 107520    // redbuf 384 floats
#define SMEM_SZ 109056

// ---------------------------------------------------------------------------
// prep: fp32 weights -> bf16 B-fragment-linear in ws (unchanged).
__global__ __launch_bounds__(256) void gb_prep_kernel(
    const float* __restrict__ Wqkv, const float* __restrict__ Wo,
    const float* __restrict__ W1,   const float* __restrict__ W2,
    __hip_bfloat16* __restrict__ ws)
{
  int fg   = blockIdx.x * 4 + (threadIdx.x >> 6);   // 0..6143
  int lane = threadIdx.x & 63;
  int layer = fg / 1536, r = fg % 1536;
  const float* src; int K, N, fl; unsigned dstbase;
  if (r < 384)       { src = Wqkv + layer*196608; K = 256;  N = 768;  fl = r;       dstbase = OWQ + layer*196608u; }
  else if (r < 512)  { src = Wo   + layer*65536;  K = 256;  N = 256;  fl = r - 384; dstbase = OWO + layer*65536u;  }
  else if (r < 1024) { src = W1   + layer*262144; K = 256;  N = 1024; fl = r - 512; dstbase = OW1 + layer*262144u; }
  else               { src = W2   + layer*262144; K = 1024; N = 256;  fl = r - 1024;dstbase = OW2 + layer*262144u; }
  int nk = K >> 5;
  int nt = fl / nk, ks = fl % nk;
  int n  = nt*16 + (lane & 15);
  int k0 = ks*32 + (lane >> 4)*8;
  __align__(16) __hip_bfloat16 tmp[8];
  #pragma unroll
  for (int j = 0; j < 8; ++j) tmp[j] = f2bf(src[(size_t)(k0 + j)*N + n]);
  *(uint4*)(ws + dstbase + (unsigned)fl*512u + lane*8) = *(const uint4*)tmp;
}

// ---------------------------------------------------------------------------
__device__ __forceinline__ void preload8(const __hip_bfloat16* __restrict__ p, bfv8 (&b)[8]) {
  #pragma unroll
  for (int k = 0; k < 8; ++k) b[k] = *(const bfv8*)(p + k*512);
}

// LayerNorm for 512 threads: thread owns column cid = tid&255, rows
// half*24..+23 (half = tid>>8). redbuf: 2 halves x 4 waves x 48 floats.
__device__ __forceinline__ void ln24h(float* z, float* redbuf, float g, float b, int tid) {
  const int lane = tid & 63;
  const int w4   = (tid >> 6) & 3;
  float* rb = redbuf + (tid >> 8)*192;
  float s1[24], s2[24];
  #pragma unroll
  for (int r = 0; r < 24; ++r) { float v = z[r]; s1[r] = v; s2[r] = v*v; }
  #pragma unroll
  for (int off = 32; off; off >>= 1) {
    #pragma unroll
    for (int r = 0; r < 24; ++r) {
      s1[r] += __shfl_down(s1[r], off, 64);
      s2[r] += __shfl_down(s2[r], off, 64);
    }
  }
  if (lane == 0) {
    #pragma unroll
    for (int r = 0; r < 24; ++r) { rb[w4*48 + r] = s1[r]; rb[w4*48 + 24 + r] = s2[r]; }
  }
  __syncthreads();
  #pragma unroll
  for (int r = 0; r < 24; ++r) {
    float S1 = rb[r] + rb[48+r] + rb[96+r] + rb[144+r];
    float S2 = rb[24+r] + rb[72+r] + rb[120+r] + rb[168+r];
    float m  = S1 * (1.0f/256.0f);
    float var = S2 * (1.0f/256.0f) - m*m;
    float iv = rsqrtf(var + 1e-5f);
    z[r] = (z[r] - m) * iv * g + b;
  }
  __syncthreads();
}

// ---------------------------------------------------------------------------
// GEMM section, 8 waves: NTI n-tiles per wave (nt = wid + 8*i), M=48 as 3
// clean 16-row tiles, depth-2 B prefetch, 6 independent MFMA chains.
template<int NTI, int NKTOT, class Epi>
__device__ __forceinline__ void gemm_sec8(const __hip_bfloat16* __restrict__ p,
                                          const bfv8 (&a)[3][8], Epi epi)
{
  const unsigned ST = 8u*(unsigned)NKTOT*512u;
  bfv8 bA[8], bB[8];
  preload8(p, bA);
  #pragma unroll
  for (int i = 0; i < NTI; i += 2) {
    preload8(p + (unsigned)(i+1)*ST, bB);
    {
      f32x4 c0a={0,0,0,0}, c0b={0,0,0,0}, c1a={0,0,0,0}, c1b={0,0,0,0};
      f32x4 c2a={0,0,0,0}, c2b={0,0,0,0};
      #pragma unroll
      for (int k = 0; k < 8; k += 2) {
        c0a = __builtin_amdgcn_mfma_f32_16x16x32_bf16(a[0][k],   bA[k],   c0a, 0,0,0);
        c1a = __builtin_amdgcn_mfma_f32_16x16x32_bf16(a[1][k],   bA[k],   c1a, 0,0,0);
        c2a = __builtin_amdgcn_mfma_f32_16x16x32_bf16(a[2][k],   bA[k],   c2a, 0,0,0);
        c0b = __builtin_amdgcn_mfma_f32_16x16x32_bf16(a[0][k+1], bA[k+1], c0b, 0,0,0);
        c1b = __builtin_amdgcn_mfma_f32_16x16x32_bf16(a[1][k+1], bA[k+1], c1b, 0,0,0);
        c2b = __builtin_amdgcn_mfma_f32_16x16x32_bf16(a[2][k+1], bA[k+1], c2b, 0,0,0);
      }
      epi(i, c0a + c0b, c1a + c1b, c2a + c2b);
    }
    if (i + 2 < NTI) preload8(p + (unsigned)(i+2)*ST, bA);
    {
      f32x4 c0a={0,0,0,0}, c0b={0,0,0,0}, c1a={0,0,0,0}, c1b={0,0,0,0};
      f32x4 c2a={0,0,0,0}, c2b={0,0,0,0};
      #pragma unroll
      for (int k = 0; k < 8; k += 2) {
        c0a = __builtin_amdgcn_mfma_f32_16x16x32_bf16(a[0][k],   bB[k],   c0a, 0,0,0);
        c1a = __builtin_amdgcn_mfma_f32_16x16x32_bf16(a[1][k],   bB[k],   c1a, 0,0,0);
        c2a = __builtin_amdgcn_mfma_f32_16x16x32_bf16(a[2][k],   bB[k],   c2a, 0,0,0);
        c0b = __builtin_amdgcn_mfma_f32_16x16x32_bf16(a[0][k+1], bB[k+1], c0b, 0,0,0);
        c1b = __builtin_amdgcn_mfma_f32_16x16x32_bf16(a[1][k+1], bB[k+1], c1b, 0,0,0);
        c2b = __builtin_amdgcn_mfma_f32_16x16x32_bf16(a[2][k+1], bB[k+1], c2b, 0,0,0);
      }
      epi(i+1, c0a + c0b, c1a + c1b, c2a + c2b);
    }
  }
}

// ---------------------------------------------------------------------------
__global__ __launch_bounds__(512, 2) void gb_mfma_kernel(
    const float* __restrict__ x,
    const float* __restrict__ W_raw, const float* __restrict__ b_raw,
    const float* __restrict__ wl_emb, const float* __restrict__ pos_emb,
    const float* __restrict__ hop_emb,
    const float* __restrict__ ln_g, const float* __restrict__ ln_b,
    const float* __restrict__ bqkv, const float* __restrict__ bo,
    const float* __restrict__ n1g,  const float* __restrict__ n1b,
    const float* __restrict__ b1,   const float* __restrict__ b2,
    const float* __restrict__ n2g,  const float* __restrict__ n2b,
    const float* __restrict__ W_res, const float* __restrict__ b_res,
    const __hip_bfloat16* __restrict__ wf,
    float* __restrict__ out)
{
  __shared__ __align__(16) char smem[SMEM_SZ];
  char* hsb = smem;                 // [48][512B] swz bf16 (h)
  char* uQ  = smem + O_R1;          // Q | xbuf | o
  char* uK  = smem + O_R2;          // K | fbuf-lo | gelu0
  char* uV  = smem + O_R3;          // V | fbuf-hi | gelu1
  float (*attw)[48][6] = (float (*)[48][6])(smem + O_ATT);
  float* redbuf = (float*)(smem + O_RED);
  float (*fbuf)[256] = (float (*)[256])(smem + O_R2);   // 48x256 fp32 = R2+R3
  float (*xbuf)[128] = (float (*)[128])(smem + O_R1);   // 48x128 fp32 = R1

  const int tid  = threadIdx.x;
  const int bt   = blockIdx.x;            // tokens bt*8 .. bt*8+7
  const int lane = tid & 63, wid = tid >> 6;
  const int l15  = lane & 15, l4 = lane >> 4;
  const int cid  = tid & 255, half = tid >> 8;

  // ---------------- Embedding: stage sub_x rows (fp32, idx mapping) --------
  for (int idx = tid; idx < TBK*6*128; idx += 512) {
    int tt = idx / 768, rem = idx % 768;
    int s = rem >> 7, f = rem & 127;
    int t = bt*TBK + tt, g = t >> 7, i = t & 127;
    int node;
    if (s < 2) node = i;
    else { int j = s - 2; node = (j < i) ? j : (j + 1); }
    xbuf[tt*6+s][f] = x[(g*128 + node)*128 + f];
  }
  __syncthreads();

  float z[24];
  {
    float (*xb)[128] = xbuf + half*24;
    #pragma unroll
    for (int r = 0; r < 24; ++r) z[r] = 0.f;
    #pragma unroll 2
    for (int f4 = 0; f4 < 32; ++f4) {
      float w0 = W_raw[(f4*4+0)*256 + cid];
      float w1 = W_raw[(f4*4+1)*256 + cid];
      float w2 = W_raw[(f4*4+2)*256 + cid];
      float w3 = W_raw[(f4*4+3)*256 + cid];
      #pragma unroll
      for (int r = 0; r < 24; ++r) {
        float4 xv = *(const float4*)(&xb[r][f4*4]);
        z[r] += xv.x*w0 + xv.y*w1 + xv.z*w2 + xv.w*w3;
      }
    }
    float br  = b_raw[cid];
    float wl  = wl_emb[cid];
    float hp0 = hop_emb[5*256 + cid];
    float hp1 = hop_emb[511*256 + cid];
    float p[6];
    #pragma unroll
    for (int s = 0; s < 6; ++s) p[s] = pos_emb[s*256 + cid];
    #pragma unroll
    for (int r = 0; r < 24; ++r) {
      int s = r % 6;   // (half*24 + r) % 6 == r % 6
      z[r] += br + p[s] + wl + ((s < 2) ? hp0 : hp1);
    }
  }
  ln24h(z, redbuf, ln_g[cid], ln_b[cid], tid);
  #pragma unroll
  for (int r = 0; r < 24; ++r)
    *(__hip_bfloat16*)(hsb + swz(half*24 + r, cid*2)) = f2bf(z[r]);

  // ---------------- res (tokens < 256 -> bt < 32), packed bf16 pairs -------
  unsigned resp[12];
  #pragma unroll
  for (int k = 0; k < 12; ++k) resp[k] = 0u;
  if (bt < 32) {
    __syncthreads();   // embed xbuf reads done (uniform branch)
    for (int idx = tid; idx < TBK*6*128; idx += 512) {
      int tt = idx / 768, rem = idx % 768;
      int s = rem >> 7, f = rem & 127;
      int t = bt*TBK + tt;
      xbuf[tt*6+s][f] = x[(t*128 + s)*128 + f];
    }
    __syncthreads();
    float (*xb)[128] = xbuf + half*24;
    float resv[24];
    float brr = b_res[cid];
    #pragma unroll
    for (int r = 0; r < 24; ++r) resv[r] = brr;
    #pragma unroll 2
    for (int f4 = 0; f4 < 32; ++f4) {
      float w0 = W_res[(f4*4+0)*256 + cid];
      float w1 = W_res[(f4*4+1)*256 + cid];
      float w2 = W_res[(f4*4+2)*256 + cid];
      float w3 = W_res[(f4*4+3)*256 + cid];
      #pragma unroll
      for (int r = 0; r < 24; ++r) {
        float4 xv = *(const float4*)(&xb[r][f4*4]);
        resv[r] += xv.x*w0 + xv.y*w1 + xv.z*w2 + xv.w*w3;
      }
    }
    #pragma unroll
    for (int k = 0; k < 12; ++k) {
      unsigned lo = __float_as_uint(resv[2*k])   >> 16;
      unsigned hi = __float_as_uint(resv[2*k+1]) & 0xffff0000u;
      resp[k] = hi | lo;
    }
  }

  // ---------------- layers ----------------
  #pragma unroll 1
  for (int l = 0; l < 4; ++l) {
    const __hip_bfloat16* WQf = wf + OWQ + (unsigned)l*196608u;
    const __hip_bfloat16* WOf = wf + OWO + (unsigned)l*65536u;
    const __hip_bfloat16* W1f = wf + OW1 + (unsigned)l*262144u;
    const __hip_bfloat16* W2f = wf + OW2 + (unsigned)l*262144u;

    float bb[6];
    #pragma unroll
    for (int i = 0; i < 6; ++i) bb[i] = bqkv[l*768 + (wid + 8*i)*16 + l15];

    __syncthreads();   // hsb visible; R1-R3 free

    // ---- QKV (N=768, K=256): 6 n-tiles/wave -> Q/K/V regions ----
    {
      bfv8 a[3][8];
      #pragma unroll
      for (int mt = 0; mt < 3; ++mt)
        #pragma unroll
        for (int ks = 0; ks < 8; ++ks)
          a[mt][ks] = *(const bfv8*)(hsb + swz(mt*16 + l15, ks*64 + l4*16));
      gemm_sec8<6, 8>(WQf + (unsigned)wid*8u*512u + lane*8, a,
        [&](int i, f32x4 c0, f32x4 c1, f32x4 c2) {
          char* qb = smem + O_R1 + (i >> 1)*24576;     // Q / K / V
          int col2 = (((i & 1)*8 + wid)*16 + l15)*2;
          float bbv = bb[i];
          #pragma unroll
          for (int j = 0; j < 4; ++j) {
            *(__hip_bfloat16*)(qb + swz(l4*4 + j,      col2)) = f2bf(c0[j] + bbv);
            *(__hip_bfloat16*)(qb + swz(16 + l4*4 + j, col2)) = f2bf(c1[j] + bbv);
            *(__hip_bfloat16*)(qb + swz(32 + l4*4 + j, col2)) = f2bf(c2[j] + bbv);
          }
        });
    }
    __syncthreads();

    // ---- scores + softmax (threads 0..383 = 8 heads x 48 rows) ----
    if (tid < 384) {
      int hh = tid / 48, r = tid % 48;
      int tr = (r / 6) * 6;
      int cbb = hh * 64;
      bfv8 qv[4];
      #pragma unroll
      for (int p4 = 0; p4 < 4; ++p4)
        qv[p4] = *(const bfv8*)(uQ + swz(r, cbb + p4*16));
      float a[6]; float mx = -1e30f;
      #pragma unroll
      for (int sp = 0; sp < 6; ++sp) {
        float s = 0.f;
        #pragma unroll
        for (int p4 = 0; p4 < 4; ++p4) {
          bfv8 kv = *(const bfv8*)(uK + swz(tr + sp, cbb + p4*16));
          #pragma unroll
          for (int j = 0; j < 8; ++j) s += bfs2f(qv[p4][j]) * bfs2f(kv[j]);
        }
        a[sp] = s * 0.17677669529663687f;   // 1/sqrt(32)
        mx = fmaxf(mx, a[sp]);
      }
      float sum = 0.f;
      #pragma unroll
      for (int sp = 0; sp < 6; ++sp) { a[sp] = __expf(a[sp] - mx); sum += a[sp]; }
      float inv = 1.f / sum;
      #pragma unroll
      for (int sp = 0; sp < 6; ++sp) attw[hh][r][sp] = a[sp] * inv;
    }
    __syncthreads();   // attw visible; Q dead

    // ---- o = a @ v -> R1 over Q. thread = (head=wid, col, token-group) ----
    {
      int hh = wid, c = lane & 31, tg = lane >> 5;
      int col2 = (hh*32 + c)*2;
      #pragma unroll
      for (int tt = 0; tt < 4; ++tt) {
        int tok = tg*4 + tt;
        float vv[6];
        #pragma unroll
        for (int sp = 0; sp < 6; ++sp)
          vv[sp] = bf2f(*(const __hip_bfloat16*)(uV + swz(tok*6 + sp, col2)));
        #pragma unroll
        for (int q = 0; q < 6; ++q) {
          float o = 0.f;
          #pragma unroll
          for (int sp = 0; sp < 6; ++sp) o += attw[hh][tok*6 + q][sp] * vv[sp];
          *(__hip_bfloat16*)(uQ + swz(tok*6 + q, col2)) = f2bf(o);
        }
      }
    }
    __syncthreads();   // o visible; K/V dead

    // ---- attn = o @ Wo -> fbuf fp32 (R2+R3) ----
    {
      bfv8 a[3][8];
      #pragma unroll
      for (int mt = 0; mt < 3; ++mt)
        #pragma unroll
        for (int ks = 0; ks < 8; ++ks)
          a[mt][ks] = *(const bfv8*)(uQ + swz(mt*16 + l15, ks*64 + l4*16));
      gemm_sec8<2, 8>(WOf + (unsigned)wid*8u*512u + lane*8, a,
        [&](int i, f32x4 c0, f32x4 c1, f32x4 c2) {
          int col = (wid + 8*i)*16 + l15;
          #pragma unroll
          for (int j = 0; j < 4; ++j) {
            fbuf[l4*4 + j][col]      = c0[j];
            fbuf[16 + l4*4 + j][col] = c1[j];
            fbuf[32 + l4*4 + j][col] = c2[j];
          }
        });
    }
    __syncthreads();   // fbuf visible

    // ---- z = h + attn + res ; LN1 ; -> hsb ----
    {
      float bov = bo[l*256 + cid];
      #pragma unroll
      for (int r = 0; r < 24; ++r)
        z[r] += unpk(resp[r >> 1], r & 1) + fbuf[half*24 + r][cid] + bov;
    }
    ln24h(z, redbuf, n1g[l*256 + cid], n1b[l*256 + cid], tid);
    #pragma unroll
    for (int r = 0; r < 24; ++r)
      *(__hip_bfloat16*)(hsb + swz(half*24 + r, cid*2)) = f2bf(z[r]);
    __syncthreads();   // hsb visible; fbuf consumed -> R2/R3 free for gelu

    // ---- FFN: 4 hidden chunks; gelu -> dbuf (R2/R3); W2 accum in regs ----
    {
      bfv8 a[3][8];
      #pragma unroll
      for (int mt = 0; mt < 3; ++mt)
        #pragma unroll
        for (int ks = 0; ks < 8; ++ks)
          a[mt][ks] = *(const bfv8*)(hsb + swz(mt*16 + l15, ks*64 + l4*16));
      f32x4 f0[3], f1[3];
      #pragma unroll
      for (int mt = 0; mt < 3; ++mt) { f0[mt] = (f32x4){0,0,0,0}; f1[mt] = (f32x4){0,0,0,0}; }

      #pragma unroll 1
      for (int ch = 0; ch < 4; ++ch) {
        char* gb = smem + ((ch & 1) ? O_R3 : O_R2);
        float bb1[2];
        #pragma unroll
        for (int i = 0; i < 2; ++i) bb1[i] = b1[l*1024 + ch*256 + (wid + 8*i)*16 + l15];

        gemm_sec8<2, 8>(W1f + (unsigned)(ch*128 + wid*8)*512u + lane*8, a,
          [&](int i, f32x4 c0, f32x4 c1, f32x4 c2) {
            int col2 = ((wid + 8*i)*16 + l15)*2;
            float bbv = bb1[i];
            #pragma unroll
            for (int j = 0; j < 4; ++j) {
              *(__hip_bfloat16*)(gb + swz(l4*4 + j,      col2)) = f2bf(gelu_f(c0[j] + bbv));
              *(__hip_bfloat16*)(gb + swz(16 + l4*4 + j, col2)) = f2bf(gelu_f(c1[j] + bbv));
              *(__hip_bfloat16*)(gb + swz(32 + l4*4 + j, col2)) = f2bf(gelu_f(c2[j] + bbv));
            }
          });
        __syncthreads();   // gelu chunk visible

        bfv8 g[3][8];
        #pragma unroll
        for (int mt = 0; mt < 3; ++mt)
          #pragma unroll
          for (int ks = 0; ks < 8; ++ks)
            g[mt][ks] = *(const bfv8*)(gb + swz(mt*16 + l15, ks*64 + l4*16));
        gemm_sec8<2, 32>(W2f + (unsigned)(wid*32 + ch*8)*512u + lane*8, g,
          [&](int i, f32x4 c0, f32x4 c1, f32x4 c2) {
            if (i == 0) { f0[0] += c0; f0[1] += c1; f0[2] += c2; }
            else        { f1[0] += c0; f1[1] += c1; f1[2] += c2; }
          });
      }
      __syncthreads();   // last gelu reads done -> R2/R3 free for fbuf
      #pragma unroll
      for (int i = 0; i < 2; ++i) {
        int col = (wid + 8*i)*16 + l15;
        #pragma unroll
        for (int j = 0; j < 4; ++j) {
          fbuf[l4*4 + j][col]      = (i ? f1[0] : f0[0])[j];
          fbuf[16 + l4*4 + j][col] = (i ? f1[1] : f0[1])[j];
          fbuf[32 + l4*4 + j][col] = (i ? f1[2] : f0[2])[j];
        }
      }
    }
    __syncthreads();   // fbuf visible

    // ---- z = h1 + ff + res ; LN2 ; -> hsb ----
    {
      float b2v = b2[l*256 + cid];
      #pragma unroll
      for (int r = 0; r < 24; ++r)
        z[r] += unpk(resp[r >> 1], r & 1) + fbuf[half*24 + r][cid] + b2v;
    }
    ln24h(z, redbuf, n2g[l*256 + cid], n2b[l*256 + cid], tid);
    #pragma unroll
    for (int r = 0; r < 24; ++r)
      *(__hip_bfloat16*)(hsb + swz(half*24 + r, cid*2)) = f2bf(z[r]);
  }

  // ---------------- output: h[:,0] ----------------
  #pragma unroll
  for (int tt = 0; tt < 4; ++tt)
    out[(bt*TBK + half*4 + tt)*256 + cid] = z[tt*6];
}

// ---------------------------------------------------------------------------
// Fallback (pure-VALU, round-2 proven, 256 threads) if ws too small.
#define NROWF 24
__device__ __forceinline__ void ln24_norm(float* z, float* redbuf, float g, float b, int tid) {
  const int lane = tid & 63, wid = tid >> 6;
  float s1[NROWF], s2[NROWF];
  #pragma unroll
  for (int r = 0; r < NROWF; ++r) { float v = z[r]; s1[r] = v; s2[r] = v*v; }
  #pragma unroll
  for (int off = 32; off; off >>= 1) {
    #pragma unroll
    for (int r = 0; r < NROWF; ++r) {
      s1[r] += __shfl_down(s1[r], off, 64);
      s2[r] += __shfl_down(s2[r], off, 64);
    }
  }
  if (lane == 0) {
    #pragma unroll
    for (int r = 0; r < NROWF; ++r) { redbuf[wid*48 + r] = s1[r]; redbuf[wid*48 + 24 + r] = s2[r]; }
  }
  __syncthreads();
  #pragma unroll
  for (int r = 0; r < NROWF; ++r) {
    float S1 = redbuf[r] + redbuf[48+r] + redbuf[96+r] + redbuf[144+r];
    float S2 = redbuf[24+r] + redbuf[72+r] + redbuf[120+r] + redbuf[168+r];
    float m  = S1 * (1.0f/256.0f);
    float var = S2 * (1.0f/256.0f) - m*m;
    float iv = rsqrtf(var + 1e-5f);
    z[r] = (z[r] - m) * iv * g + b;
  }
  __syncthreads();
}

__global__ __launch_bounds__(256, 2) void gb_fused_fallback(
    const float* __restrict__ x,
    const float* __restrict__ W_raw, const float* __restrict__ b_raw,
    const float* __restrict__ wl_emb, const float* __restrict__ pos_emb,
    const float* __restrict__ hop_emb,
    const float* __restrict__ ln_g, const float* __restrict__ ln_b,
    const float* __restrict__ Wqkv, const float* __restrict__ bqkv,
    const float* __restrict__ Wo,   const float* __restrict__ bo,
    const float* __restrict__ n1g,  const float* __restrict__ n1b,
    const float* __restrict__ W1,   const float* __restrict__ b1,
    const float* __restrict__ W2,   const float* __restrict__ b2,
    const float* __restrict__ n2g,  const float* __restrict__ n2b,
    const float* __restrict__ W_res, const float* __restrict__ b_res,
    float* __restrict__ out)
{
  __shared__ float hs[NROWF][256];
  __shared__ __align__(16) char bufraw[NROWF*768*2];
  __shared__ float attw[8][NROWF][8];
  __shared__ float redbuf[192];

  __hip_bfloat16 (*qkvs)[768] = (__hip_bfloat16 (*)[768])bufraw;
  float (*fbuf)[256] = (float (*)[256])bufraw;
  float (*xbuf)[128] = (float (*)[128])bufraw;

  const int tid = threadIdx.x;
  const int bt  = blockIdx.x;

  for (int idx = tid; idx < 4*6*128; idx += 256) {
    int tt = idx / 768, rem = idx % 768;
    int s = rem >> 7, f = rem & 127;
    int t = bt*4 + tt, g = t >> 7, i = t & 127;
    int node;
    if (s < 2) node = i;
    else { int j = s - 2; node = (j < i) ? j : (j + 1); }
    xbuf[tt*6+s][f] = x[(g*128 + node)*128 + f];
  }
  __syncthreads();

  float z[NROWF];
  {
    #pragma unroll
    for (int r = 0; r < NROWF; ++r) z[r] = 0.f;
    #pragma unroll 4
    for (int f = 0; f < 128; ++f) {
      float w = W_raw[f*256 + tid];
      #pragma unroll
      for (int r = 0; r < NROWF; ++r) z[r] += xbuf[r][f] * w;
    }
    float br  = b_raw[tid];
    float wl  = wl_emb[tid];
    float hp0 = hop_emb[5*256 + tid];
    float hp1 = hop_emb[511*256 + tid];
    float p[6];
    #pragma unroll
    for (int s = 0; s < 6; ++s) p[s] = pos_emb[s*256 + tid];
    #pragma unroll
    for (int r = 0; r < NROWF; ++r) {
      int s = r % 6;
      z[r] += br + p[s] + wl + ((s < 2) ? hp0 : hp1);
    }
  }
  ln24_norm(z, redbuf, ln_g[tid], ln_b[tid], tid);
  #pragma unroll
  for (int r = 0; r < NROWF; ++r) hs[r][tid] = z[r];

  float resv[NROWF];
  #pragma unroll
  for (int r = 0; r < NROWF; ++r) resv[r] = 0.f;
  if (bt < 64) {
    __syncthreads();
    for (int idx = tid; idx < 4*6*128; idx += 256) {
      int tt = idx / 768, rem = idx % 768;
      int s = rem >> 7, f = rem & 127;
      int t = bt*4 + tt;
      xbuf[tt*6+s][f] = x[(t*128 + s)*128 + f];
    }
    __syncthreads();
    #pragma unroll 4
    for (int f = 0; f < 128; ++f) {
      float w = W_res[f*256 + tid];
      #pragma unroll
      for (int r = 0; r < NROWF; ++r) resv[r] += xbuf[r][f] * w;
    }
    float brr = b_res[tid];
    #pragma unroll
    for (int r = 0; r < NROWF; ++r) resv[r] += brr;
  }

  for (int l = 0; l < 4; ++l) {
    const float* Wqkv_l = Wqkv + l*196608;
    const float* bqkv_l = bqkv + l*768;
    const float* Wo_l   = Wo   + l*65536;
    const float* bo_l   = bo   + l*256;
    const float* W1_l   = W1   + l*262144;
    const float* b1_l   = b1   + l*1024;
    const float* W2_l   = W2   + l*262144;
    const float* b2_l   = b2   + l*256;

    __syncthreads();

    for (int cg = 0; cg < 3; ++cg) {
      int col = cg*256 + tid;
      float acc[NROWF];
      #pragma unroll
      for (int r = 0; r < NROWF; ++r) acc[r] = 0.f;
      #pragma unroll 4
      for (int kk = 0; kk < 256; ++kk) {
        float w = Wqkv_l[kk*768 + col];
        #pragma unroll
        for (int r = 0; r < NROWF; ++r) acc[r] += hs[r][kk] * w;
      }
      float bbv = bqkv_l[col];
      #pragma unroll
      for (int r = 0; r < NROWF; ++r) qkvs[r][col] = f2bf(acc[r] + bbv);
    }
    __syncthreads();

    #pragma unroll 1
    for (int it = 0; it < 5; ++it) {
      int idx = it*256 + tid;
      if (idx < 1152) {
        int hh = idx / 144, rem = idx % 144;
        int r = rem / 6, sp = rem % 6;
        int tt6 = (r / 6) * 6;
        float sc = 0.f;
        #pragma unroll
        for (int c = 0; c < 32; ++c)
          sc += bf2f(qkvs[r][hh*32 + c]) * bf2f(qkvs[tt6 + sp][256 + hh*32 + c]);
        attw[hh][r][sp] = sc * 0.17677669529663687f;
      }
    }
    __syncthreads();

    if (tid < 192) {
      int hh = tid / 24, r = tid % 24;
      float mx = attw[hh][r][0];
      #pragma unroll
      for (int sp = 1; sp < 6; ++sp) mx = fmaxf(mx, attw[hh][r][sp]);
      float e[6], sum = 0.f;
      #pragma unroll
      for (int sp = 0; sp < 6; ++sp) { e[sp] = expf(attw[hh][r][sp] - mx); sum += e[sp]; }
      float inv = 1.f / sum;
      #pragma unroll
      for (int sp = 0; sp < 6; ++sp) attw[hh][r][sp] = e[sp] * inv;
    }
    __syncthreads();

    float oreg[NROWF];
    {
      int hh = tid >> 5, c = tid & 31;
      #pragma unroll
      for (int r = 0; r < NROWF; ++r) {
        int tt6 = (r / 6) * 6;
        float o = 0.f;
        #pragma unroll
        for (int sp = 0; sp < 6; ++sp)
          o += attw[hh][r][sp] * bf2f(qkvs[tt6 + sp][512 + hh*32 + c]);
        oreg[r] = o;
      }
    }
    __syncthreads();
    #pragma unroll
    for (int r = 0; r < NROWF; ++r) fbuf[r][tid] = oreg[r];
    __syncthreads();

    {
      float bod = bo_l[tid];
      float zz[NROWF];
      #pragma unroll
      for (int r = 0; r < NROWF; ++r) zz[r] = bod;
      #pragma unroll 4
      for (int kk = 0; kk < 256; ++kk) {
        float w = Wo_l[kk*256 + tid];
        #pragma unroll
        for (int r = 0; r < NROWF; ++r) zz[r] += fbuf[r][kk] * w;
      }
      #pragma unroll
      for (int r = 0; r < NROWF; ++r) z[r] += zz[r] + resv[r];
    }
    ln24_norm(z, redbuf, n1g[l*256 + tid], n1b[l*256 + tid], tid);
    #pragma unroll
    for (int r = 0; r < NROWF; ++r) hs[r][tid] = z[r];
    __syncthreads();

    float ff[NROWF];
    {
      float b2d = b2_l[tid];
      #pragma unroll
      for (int r = 0; r < NROWF; ++r) ff[r] = b2d;
    }
    for (int ch = 0; ch < 4; ++ch) {
      int j = ch*256 + tid;
      float gvv[NROWF];
      float b1j = b1_l[j];
      #pragma unroll
      for (int r = 0; r < NROWF; ++r) gvv[r] = b1j;
      #pragma unroll 4
      for (int kk = 0; kk < 256; ++kk) {
        float w = W1_l[kk*1024 + j];
        #pragma unroll
        for (int r = 0; r < NROWF; ++r) gvv[r] += hs[r][kk] * w;
      }
      __syncthreads();
      #pragma unroll
      for (int r = 0; r < NROWF; ++r) fbuf[r][tid] = gelu_f(gvv[r]);
      __syncthreads();
      #pragma unroll 4
      for (int kk = 0; kk < 256; ++kk) {
        float w = W2_l[(ch*256 + kk)*256 + tid];
        #pragma unroll
        for (int r = 0; r < NROWF; ++r) ff[r] += fbuf[r][kk] * w;
      }
    }
    #pragma unroll
    for (int r = 0; r < NROWF; ++r) z[r] += ff[r] + resv[r];
    ln24_norm(z, redbuf, n2g[l*256 + tid], n2b[l*256 + tid], tid);
    #pragma unroll
    for (int r = 0; r < NROWF; ++r) hs[r][tid] = z[r];
  }

  __syncthreads();
  #pragma unroll
  for (int tt = 0; tt < 4; ++tt)
    out[(bt*4 + tt)*256 + tid] = hs[tt*6][tid];
}

extern "C" void kernel_launch(void* const* d_in, const int* in_sizes, int n_in,
                              void* d_out, int out_size, void* d_ws, size_t ws_size,
                              hipStream_t stream) {
  (void)in_sizes; (void)n_in; (void)out_size;
  const float* x      = (const float*)d_in[0];
  const float* W_raw  = (const float*)d_in[1];
  const float* b_raw  = (const float*)d_in[2];
  const float* wl_emb = (const float*)d_in[3];
  const float* pos_emb= (const float*)d_in[4];
  const float* hop_emb= (const float*)d_in[5];
  const float* ln_g   = (const float*)d_in[6];
  const float* ln_b   = (const float*)d_in[7];
  const float* Wqkv   = (const float*)d_in[8];
  const float* bqkv   = (const float*)d_in[9];
  const float* Wo     = (const float*)d_in[10];
  const float* bo     = (const float*)d_in[11];
  const float* n1g    = (const float*)d_in[12];
  const float* n1b    = (const float*)d_in[13];
  const float* W1     = (const float*)d_in[14];
  const float* b1     = (const float*)d_in[15];
  const float* W2     = (const float*)d_in[16];
  const float* b2     = (const float*)d_in[17];
  const float* n2g    = (const float*)d_in[18];
  const float* n2b    = (const float*)d_in[19];
  const float* W_res  = (const float*)d_in[20];
  const float* b_res  = (const float*)d_in[21];

  if (ws_size >= (size_t)WS_ELEMS * 2) {
    __hip_bfloat16* wsb = (__hip_bfloat16*)d_ws;
    gb_prep_kernel<<<1536, 256, 0, stream>>>(Wqkv, Wo, W1, W2, wsb);
    gb_mfma_kernel<<<4096, 512, 0, stream>>>(
        x, W_raw, b_raw, wl_emb, pos_emb, hop_emb, ln_g, ln_b,
        bqkv, bo, n1g, n1b, b1, b2, n2g, n2b, W_res, b_res,
        wsb, (float*)d_out);
  } else {
    gb_fused_fallback<<<8192, 256, 0, stream>>>(
        x, W_raw, b_raw, wl_emb, pos_emb, hop_emb, ln_g, ln_b,
        Wqkv, bqkv, Wo, bo, n1g, n1b, W1, b1, W2, b2, n2g, n2b,
        W_res, b_res, (float*)d_out);
  }
}

// Round 10
// 6428.151 us; speedup vs baseline: 1.4134x; 1.3817x over previous
//
#include <hip/hip_runtime.h>
#include <hip/hip_bf16.h>

// GraphBertEncoder: T=32768 tokens, S=6, D=256, H=8 (hd=32), L=4.
// Round 10: round-4 skeleton (proven 6.41ms: phases, barriers, LDS layout,
// 2 blocks/CU, depth-style B prefetch, no setprio) with GEMM sections
// redesigned to FIT 128 VGPRs (the empirical compiler cap) with no spills:
//  - K-split gemm_ks: A[2][4]=32 (reload per K-half from LDS), B depth-3
//    rotating buffer=48, C[4][2]=32  -> peak ~112 regs
//  - z parked in LDS (residual re-read from hsb bf16 at LN points)
//  - W2 accumulates into LDS bf16 (uB) instead of 32 persistent facc regs

#define TB 4
#define NROW 24

typedef float f32x4 __attribute__((ext_vector_type(4)));
typedef short bfv8  __attribute__((ext_vector_type(8)));   // 8 bf16 = 4 VGPR

__device__ __forceinline__ float bf2f(__hip_bfloat16 v) { return __bfloat162float(v); }
__device__ __forceinline__ __hip_bfloat16 f2bf(float v) { return __float2bfloat16(v); }
__device__ __forceinline__ float bfs2f(short s) { return __uint_as_float(((unsigned)(unsigned short)s) << 16); }
// swizzled byte offset into a [32][512B] bf16 tile (row stride 512B)
__device__ __forceinline__ int swz(int row, int cb) { return row*512 + (cb ^ ((row & 7) << 4)); }
__device__ __forceinline__ float gelu_f(float v) { return 0.5f*v*(1.f + erff(v*0.70710678118654752f)); }
__device__ __forceinline__ float unpk(unsigned p, int hi) {
  return __uint_as_float(hi ? (p & 0xffff0000u) : (p << 16));
}

// ws fragment-layout offsets (bf16 elements)
#define OWQ 0u
#define OWO 786432u
#define OW1 1048576u
#define OW2 2097152u
#define WS_ELEMS 3145728u   // *2B = 6291456 bytes

// ---------------------------------------------------------------------------
// prep: fp32 weights -> bf16 B-fragment-linear in ws (unchanged).
__global__ __launch_bounds__(256) void gb_prep_kernel(
    const float* __restrict__ Wqkv, const float* __restrict__ Wo,
    const float* __restrict__ W1,   const float* __restrict__ W2,
    __hip_bfloat16* __restrict__ ws)
{
  int fg   = blockIdx.x * 4 + (threadIdx.x >> 6);   // 0..6143
  int lane = threadIdx.x & 63;
  int layer = fg / 1536, r = fg % 1536;
  const float* src; int K, N, fl; unsigned dstbase;
  if (r < 384)       { src = Wqkv + layer*196608; K = 256;  N = 768;  fl = r;       dstbase = OWQ + layer*196608u; }
  else if (r < 512)  { src = Wo   + layer*65536;  K = 256;  N = 256;  fl = r - 384; dstbase = OWO + layer*65536u;  }
  else if (r < 1024) { src = W1   + layer*262144; K = 256;  N = 1024; fl = r - 512; dstbase = OW1 + layer*262144u; }
  else               { src = W2   + layer*262144; K = 1024; N = 256;  fl = r - 1024;dstbase = OW2 + layer*262144u; }
  int nk = K >> 5;
  int nt = fl / nk, ks = fl % nk;
  int n  = nt*16 + (lane & 15);
  int k0 = ks*32 + (lane >> 4)*8;
  __align__(16) __hip_bfloat16 tmp[8];
  #pragma unroll
  for (int j = 0; j < 8; ++j) tmp[j] = f2bf(src[(size_t)(k0 + j)*N + n]);
  *(uint4*)(ws + dstbase + (unsigned)fl*512u + lane*8) = *(const uint4*)tmp;
}

// ---------------------------------------------------------------------------
// one-pass LayerNorm over 256 columns for 24 rows (thread owns column tid).
__device__ __forceinline__ void ln24_norm(float* z, float* redbuf, float g, float b, int tid) {
  const int lane = tid & 63, wid = tid >> 6;
  float s1[NROW], s2[NROW];
  #pragma unroll
  for (int r = 0; r < NROW; ++r) { float v = z[r]; s1[r] = v; s2[r] = v*v; }
  #pragma unroll
  for (int off = 32; off; off >>= 1) {
    #pragma unroll
    for (int r = 0; r < NROW; ++r) {
      s1[r] += __shfl_down(s1[r], off, 64);
      s2[r] += __shfl_down(s2[r], off, 64);
    }
  }
  if (lane == 0) {
    #pragma unroll
    for (int r = 0; r < NROW; ++r) { redbuf[wid*48 + r] = s1[r]; redbuf[wid*48 + 24 + r] = s2[r]; }
  }
  __syncthreads();
  #pragma unroll
  for (int r = 0; r < NROW; ++r) {
    float S1 = redbuf[r] + redbuf[48+r] + redbuf[96+r] + redbuf[144+r];
    float S2 = redbuf[24+r] + redbuf[72+r] + redbuf[120+r] + redbuf[168+r];
    float m  = S1 * (1.0f/256.0f);
    float var = S2 * (1.0f/256.0f) - m*m;
    float iv = rsqrtf(var + 1e-5f);
    z[r] = (z[r] - m) * iv * g + b;
  }
  __syncthreads();
}

// ---------------------------------------------------------------------------
// K-split GEMM sub-section: 4 n-tiles per wave (nt = base + i*4), K=256 as
// two halves (kh). A[2][4] reloaded per kh via loadA; B depth-3 rotating
// prefetch (2 K-half-steps = 4KB in flight); C[4][2] zero-inited here.
// Step s = kh*4 + i; B addr = p + (s&3)*ST + (s>>2)*2048 (+k*512).
template<int NKTOT, class LoadA>
__device__ __forceinline__ void gemm_ks(const __hip_bfloat16* __restrict__ p,
                                        LoadA loadA, f32x4 (&C)[4][2])
{
  const unsigned ST = 4u*(unsigned)NKTOT*512u;
  bfv8 B[3][4];
  bfv8 a[2][4];
  #pragma unroll
  for (int i = 0; i < 4; ++i) {
    C[i][0] = (f32x4){0.f,0.f,0.f,0.f};
    C[i][1] = (f32x4){0.f,0.f,0.f,0.f};
  }
  #pragma unroll
  for (int k = 0; k < 4; ++k) B[0][k] = *(const bfv8*)(p + k*512);
  {
    const __hip_bfloat16* q = p + ST;
    #pragma unroll
    for (int k = 0; k < 4; ++k) B[1][k] = *(const bfv8*)(q + k*512);
  }
  loadA(0, a);
  #pragma unroll
  for (int s = 0; s < 8; ++s) {
    if (s + 2 < 8) {
      const __hip_bfloat16* q = p + (unsigned)((s+2) & 3)*ST + (unsigned)((s+2) >> 2)*2048u;
      #pragma unroll
      for (int k = 0; k < 4; ++k) B[(s+2)%3][k] = *(const bfv8*)(q + k*512);
    }
    if (s == 4) loadA(1, a);
    #pragma unroll
    for (int k = 0; k < 4; ++k) {
      C[s&3][0] = __builtin_amdgcn_mfma_f32_16x16x32_bf16(a[0][k], B[s%3][k], C[s&3][0], 0,0,0);
      C[s&3][1] = __builtin_amdgcn_mfma_f32_16x16x32_bf16(a[1][k], B[s%3][k], C[s&3][1], 0,0,0);
    }
  }
}

// ---------------------------------------------------------------------------
__global__ __launch_bounds__(256, 2) void gb_mfma_kernel(
    const float* __restrict__ x,
    const float* __restrict__ W_raw, const float* __restrict__ b_raw,
    const float* __restrict__ wl_emb, const float* __restrict__ pos_emb,
    const float* __restrict__ hop_emb,
    const float* __restrict__ ln_g, const float* __restrict__ ln_b,
    const float* __restrict__ bqkv, const float* __restrict__ bo,
    const float* __restrict__ n1g,  const float* __restrict__ n1b,
    const float* __restrict__ b1,   const float* __restrict__ b2,
    const float* __restrict__ n2g,  const float* __restrict__ n2b,
    const float* __restrict__ W_res, const float* __restrict__ b_res,
    const __hip_bfloat16* __restrict__ wf,
    float* __restrict__ out)
{
  // LDS: hsb 16K | uA 37248 (xbuf fp32 | qkvs bf16 | fbuf fp32 | gelu dbuf 2x16K)
  //      uB 16K (o swz bf16 / ff accum bf16) | attw 4608 | redbuf 768 => 75392
  __shared__ __align__(16) char smem[75392];
  char* hsb = smem;                              // [32][512B] swz bf16
  char* uA  = smem + 16384;
  char* uB  = smem + 53632;                      // [32][512B]
  float (*attw)[24][6] = (float (*)[24][6])(smem + 70016);
  float* redbuf = (float*)(smem + 74624);

  __hip_bfloat16 (*qkvs)[776] = (__hip_bfloat16 (*)[776])uA;
  float (*fbuf)[264] = (float (*)[264])uA;
  float (*xbuf)[128] = (float (*)[128])uA;

  const int tid  = threadIdx.x;
  const int bt   = blockIdx.x;
  const int lane = tid & 63, wid = tid >> 6;
  const int l15  = lane & 15, l4 = lane >> 4;

  // A-fragment loader factory (swizzled 32-row bf16 buffers)
  auto mkA = [l15, l4](const char* buf) {
    return [buf, l15, l4](int kh, bfv8 (&a)[2][4]) {
      #pragma unroll
      for (int k = 0; k < 4; ++k) {
        a[0][k] = *(const bfv8*)(buf + swz(l15,      (kh*4 + k)*64 + l4*16));
        a[1][k] = *(const bfv8*)(buf + swz(16 + l15, (kh*4 + k)*64 + l4*16));
      }
    };
  };

  // zero rows 24-31 of hsb and uB once (A-fragments read rows 16..31)
  {
    uint4 zz = {0u,0u,0u,0u};
    *(uint4*)(hsb + 24*512 + tid*16) = zz;
    *(uint4*)(uB  + 24*512 + tid*16) = zz;
  }

  // ---------------- Embedding: stage sub_x rows (fp32, idx mapping) --------
  for (int idx = tid; idx < TB*6*128; idx += 256) {
    int tt = idx / 768, rem = idx % 768;
    int s = rem >> 7, f = rem & 127;
    int t = bt*TB + tt, g = t >> 7, i = t & 127;
    int node;
    if (s < 2) node = i;
    else { int j = s - 2; node = (j < i) ? j : (j + 1); }
    xbuf[tt*6+s][f] = x[(g*128 + node)*128 + f];
  }
  __syncthreads();

  {
    float z[NROW];
    #pragma unroll
    for (int r = 0; r < NROW; ++r) z[r] = 0.f;
    #pragma unroll 2
    for (int f4 = 0; f4 < 32; ++f4) {
      float w0 = W_raw[(f4*4+0)*256 + tid];
      float w1 = W_raw[(f4*4+1)*256 + tid];
      float w2 = W_raw[(f4*4+2)*256 + tid];
      float w3 = W_raw[(f4*4+3)*256 + tid];
      #pragma unroll
      for (int r = 0; r < NROW; ++r) {
        float4 xv = *(const float4*)(&xbuf[r][f4*4]);
        z[r] += xv.x*w0 + xv.y*w1 + xv.z*w2 + xv.w*w3;
      }
    }
    float br  = b_raw[tid];
    float wl  = wl_emb[tid];
    float hp0 = hop_emb[5*256 + tid];
    float hp1 = hop_emb[511*256 + tid];
    float p[6];
    #pragma unroll
    for (int s = 0; s < 6; ++s) p[s] = pos_emb[s*256 + tid];
    #pragma unroll
    for (int r = 0; r < NROW; ++r) {
      int s = r % 6;
      z[r] += br + p[s] + wl + ((s < 2) ? hp0 : hp1);
    }
    ln24_norm(z, redbuf, ln_g[tid], ln_b[tid], tid);
    #pragma unroll
    for (int r = 0; r < NROW; ++r)
      *(__hip_bfloat16*)(hsb + swz(r, tid*2)) = f2bf(z[r]);
  }

  // ---------------- res (bt<64 only), packed bf16 pairs --------------------
  unsigned resp[12];
  #pragma unroll
  for (int k = 0; k < 12; ++k) resp[k] = 0u;
  if (bt < 64) {
    __syncthreads();   // embed xbuf reads done (uniform branch)
    for (int idx = tid; idx < TB*6*128; idx += 256) {
      int tt = idx / 768, rem = idx % 768;
      int s = rem >> 7, f = rem & 127;
      int t = bt*TB + tt;
      xbuf[tt*6+s][f] = x[(t*128 + s)*128 + f];
    }
    __syncthreads();
    float resv[NROW];
    float brr = b_res[tid];
    #pragma unroll
    for (int r = 0; r < NROW; ++r) resv[r] = brr;
    #pragma unroll 2
    for (int f4 = 0; f4 < 32; ++f4) {
      float w0 = W_res[(f4*4+0)*256 + tid];
      float w1 = W_res[(f4*4+1)*256 + tid];
      float w2 = W_res[(f4*4+2)*256 + tid];
      float w3 = W_res[(f4*4+3)*256 + tid];
      #pragma unroll
      for (int r = 0; r < NROW; ++r) {
        float4 xv = *(const float4*)(&xbuf[r][f4*4]);
        resv[r] += xv.x*w0 + xv.y*w1 + xv.z*w2 + xv.w*w3;
      }
    }
    #pragma unroll
    for (int k = 0; k < 12; ++k) {
      unsigned lo = __float_as_uint(resv[2*k])   >> 16;
      unsigned hi = __float_as_uint(resv[2*k+1]) & 0xffff0000u;
      resp[k] = hi | lo;
    }
  }

  float z[NROW];   // live only within LN/residual/output phases

  // ---------------- layers ----------------
  #pragma unroll 1
  for (int l = 0; l < 4; ++l) {
    const __hip_bfloat16* WQf = wf + OWQ + (unsigned)l*196608u;
    const __hip_bfloat16* WOf = wf + OWO + (unsigned)l*65536u;
    const __hip_bfloat16* W1f = wf + OW1 + (unsigned)l*262144u;
    const __hip_bfloat16* W2f = wf + OW2 + (unsigned)l*262144u;

    __syncthreads();   // hsb visible; uA/uB free

    // ---- QKV (N=768, K=256): 3 sub-sections of 4 n-tiles ----
    {
      auto lA = mkA(hsb);
      #pragma unroll 1
      for (int sub = 0; sub < 3; ++sub) {
        f32x4 C[4][2];
        gemm_ks<8>(WQf + (unsigned)(sub*16 + wid)*8u*512u + lane*8, lA, C);
        #pragma unroll
        for (int i = 0; i < 4; ++i) {
          int gcol = sub*256 + (wid + i*4)*16 + l15;
          float bbv = bqkv[l*768 + gcol];
          #pragma unroll
          for (int j = 0; j < 4; ++j) {
            qkvs[l4*4 + j][gcol] = f2bf(C[i][0][j] + bbv);
            int r1 = 16 + l4*4 + j;
            if (r1 < NROW) qkvs[r1][gcol] = f2bf(C[i][1][j] + bbv);
          }
        }
      }
    }
    __syncthreads();

    // ---- scores + softmax fused (threads 0..191: (head, row)) ----
    if (tid < 192) {
      int hh = tid / 24, r = tid % 24;
      int tt6 = (r / 6) * 6;
      bfv8 qv[4];
      #pragma unroll
      for (int p4 = 0; p4 < 4; ++p4) qv[p4] = *(const bfv8*)(&qkvs[r][hh*32 + p4*8]);
      float sc[6];
      #pragma unroll
      for (int sp = 0; sp < 6; ++sp) {
        float s = 0.f;
        #pragma unroll
        for (int p4 = 0; p4 < 4; ++p4) {
          bfv8 kv = *(const bfv8*)(&qkvs[tt6 + sp][256 + hh*32 + p4*8]);
          #pragma unroll
          for (int j = 0; j < 8; ++j) s += bfs2f(qv[p4][j]) * bfs2f(kv[j]);
        }
        sc[sp] = s * 0.17677669529663687f;   // 1/sqrt(32)
      }
      float mx = sc[0];
      #pragma unroll
      for (int sp = 1; sp < 6; ++sp) mx = fmaxf(mx, sc[sp]);
      float sum = 0.f;
      #pragma unroll
      for (int sp = 0; sp < 6; ++sp) { sc[sp] = __expf(sc[sp] - mx); sum += sc[sp]; }
      float inv = 1.f / sum;
      #pragma unroll
      for (int sp = 0; sp < 6; ++sp) attw[hh][r][sp] = sc[sp] * inv;
    }
    __syncthreads();

    // ---- o = a @ v -> uB (swz bf16). thread owns (head hh, col c) ----
    {
      int hh = tid >> 5, c = tid & 31;
      int col2 = (hh*32 + c)*2;
      #pragma unroll
      for (int tt = 0; tt < 4; ++tt) {
        float vv[6];
        #pragma unroll
        for (int sp = 0; sp < 6; ++sp) vv[sp] = bf2f(qkvs[tt*6 + sp][512 + hh*32 + c]);
        #pragma unroll
        for (int q = 0; q < 6; ++q) {
          float o = 0.f;
          #pragma unroll
          for (int sp = 0; sp < 6; ++sp) o += attw[hh][tt*6 + q][sp] * vv[sp];
          *(__hip_bfloat16*)(uB + swz(tt*6 + q, col2)) = f2bf(o);
        }
      }
    }
    __syncthreads();   // uB(o) ready; qkvs dead -> fbuf writable

    // ---- attn = o @ Wo -> fbuf fp32 ----
    {
      f32x4 C[4][2];
      gemm_ks<8>(WOf + (unsigned)wid*8u*512u + lane*8, mkA(uB), C);
      #pragma unroll
      for (int i = 0; i < 4; ++i) {
        int col = (wid + i*4)*16 + l15;
        #pragma unroll
        for (int j = 0; j < 4; ++j) {
          fbuf[l4*4 + j][col] = C[i][0][j];
          int r1 = 16 + l4*4 + j;
          if (r1 < NROW) fbuf[r1][col] = C[i][1][j];
        }
      }
    }
    __syncthreads();   // fbuf visible; uB(o) dead

    // ---- z = h + attn + res ; LN1 ; -> hsb. Also zero uB ff-accum rows ----
    {
      float bov = bo[l*256 + tid];
      #pragma unroll
      for (int r = 0; r < NROW; ++r)
        z[r] = bf2f(*(const __hip_bfloat16*)(hsb + swz(r, tid*2)))
             + unpk(resp[r >> 1], r & 1) + fbuf[r][tid] + bov;
    }
    #pragma unroll
    for (int k = 0; k < 12; ++k) *(unsigned*)(uB + (k*256 + tid)*4) = 0u;  // rows 0-23
    ln24_norm(z, redbuf, n1g[l*256 + tid], n1b[l*256 + tid], tid);
    #pragma unroll
    for (int r = 0; r < NROW; ++r)
      *(__hip_bfloat16*)(hsb + swz(r, tid*2)) = f2bf(z[r]);
    // zero rows 24-31 of both gelu buffers (clobbered by qkvs earlier)
    {
      uint4 zz = {0u,0u,0u,0u};
      *(uint4*)(uA + 24*512 + tid*16) = zz;
      *(uint4*)(uA + 16384 + 24*512 + tid*16) = zz;
    }
    __syncthreads();   // hsb + gelu-tails + uB-zero visible

    // ---- FFN: 4 hidden chunks; gelu -> dbuf LDS; W2 accumulates in uB bf16
    {
      auto lAh = mkA(hsb);
      #pragma unroll 1
      for (int ch = 0; ch < 4; ++ch) {
        char* gb = uA + (ch & 1)*16384;
        {
          f32x4 C[4][2];
          gemm_ks<8>(W1f + (unsigned)(ch*128 + wid*8)*512u + lane*8, lAh, C);
          #pragma unroll
          for (int i = 0; i < 4; ++i) {
            float bbv = b1[l*1024 + ch*256 + (wid + i*4)*16 + l15];
            int col2 = ((wid + i*4)*16 + l15)*2;
            #pragma unroll
            for (int j = 0; j < 4; ++j) {
              *(__hip_bfloat16*)(gb + swz(l4*4 + j, col2)) = f2bf(gelu_f(C[i][0][j] + bbv));
              int r1 = 16 + l4*4 + j;
              if (r1 < NROW)
                *(__hip_bfloat16*)(gb + swz(r1, col2)) = f2bf(gelu_f(C[i][1][j] + bbv));
            }
          }
        }
        __syncthreads();   // gelu chunk visible

        {
          f32x4 C[4][2];
          gemm_ks<32>(W2f + (unsigned)(wid*32 + ch*8)*512u + lane*8, mkA(gb), C);
          // thread-owned RMW accumulate into uB bf16 [24][256] (512B stride)
          #pragma unroll
          for (int i = 0; i < 4; ++i) {
            int col2 = ((wid + i*4)*16 + l15)*2;
            #pragma unroll
            for (int j = 0; j < 4; ++j) {
              {
                __hip_bfloat16* pp = (__hip_bfloat16*)(uB + (l4*4 + j)*512 + col2);
                *pp = f2bf(bf2f(*pp) + C[i][0][j]);
              }
              int r1 = 16 + l4*4 + j;
              if (r1 < NROW) {
                __hip_bfloat16* pp = (__hip_bfloat16*)(uB + r1*512 + col2);
                *pp = f2bf(bf2f(*pp) + C[i][1][j]);
              }
            }
          }
        }
      }
    }
    __syncthreads();   // all ff accumulation visible

    // ---- z = h1 + ff + res ; LN2 ; -> hsb ----
    {
      float b2v = b2[l*256 + tid];
      #pragma unroll
      for (int r = 0; r < NROW; ++r)
        z[r] = bf2f(*(const __hip_bfloat16*)(hsb + swz(r, tid*2)))
             + unpk(resp[r >> 1], r & 1)
             + bf2f(*(const __hip_bfloat16*)(uB + r*512 + tid*2)) + b2v;
    }
    ln24_norm(z, redbuf, n2g[l*256 + tid], n2b[l*256 + tid], tid);
    #pragma unroll
    for (int r = 0; r < NROW; ++r)
      *(__hip_bfloat16*)(hsb + swz(r, tid*2)) = f2bf(z[r]);
    // restore uB tail zeros not needed: ff accum stayed in rows 0-23 (512B stride)
  }

  // ---------------- output: h[:,0] ----------------
  #pragma unroll
  for (int tt = 0; tt < TB; ++tt)
    out[(bt*TB + tt)*256 + tid] = z[tt*6];
}

// ---------------------------------------------------------------------------
// Fallback (pure-VALU, round-2 proven) if ws too small for weight staging.
__global__ __launch_bounds__(256, 2) void gb_fused_fallback(
    const float* __restrict__ x,
    const float* __restrict__ W_raw, const float* __restrict__ b_raw,
    const float* __restrict__ wl_emb, const float* __restrict__ pos_emb,
    const float* __restrict__ hop_emb,
    const float* __restrict__ ln_g, const float* __restrict__ ln_b,
    const float* __restrict__ Wqkv, const float* __restrict__ bqkv,
    const float* __restrict__ Wo,   const float* __restrict__ bo,
    const float* __restrict__ n1g,  const float* __restrict__ n1b,
    const float* __restrict__ W1,   const float* __restrict__ b1,
    const float* __restrict__ W2,   const float* __restrict__ b2,
    const float* __restrict__ n2g,  const float* __restrict__ n2b,
    const float* __restrict__ W_res, const float* __restrict__ b_res,
    float* __restrict__ out)
{
  __shared__ float hs[NROW][256];
  __shared__ __align__(16) char bufraw[NROW*768*2];
  __shared__ float attw[8][NROW][8];
  __shared__ float redbuf[192];

  __hip_bfloat16 (*qkvs)[768] = (__hip_bfloat16 (*)[768])bufraw;
  float (*fbuf)[256] = (float (*)[256])bufraw;
  float (*xbuf)[128] = (float (*)[128])bufraw;

  const int tid = threadIdx.x;
  const int bt  = blockIdx.x;

  for (int idx = tid; idx < TB*6*128; idx += 256) {
    int tt = idx / 768, rem = idx % 768;
    int s = rem >> 7, f = rem & 127;
    int t = bt*TB + tt, g = t >> 7, i = t & 127;
    int node;
    if (s < 2) node = i;
    else { int j = s - 2; node = (j < i) ? j : (j + 1); }
    xbuf[tt*6+s][f] = x[(g*128 + node)*128 + f];
  }
  __syncthreads();

  float z[NROW];
  {
    #pragma unroll
    for (int r = 0; r < NROW; ++r) z[r] = 0.f;
    #pragma unroll 4
    for (int f = 0; f < 128; ++f) {
      float w = W_raw[f*256 + tid];
      #pragma unroll
      for (int r = 0; r < NROW; ++r) z[r] += xbuf[r][f] * w;
    }
    float br  = b_raw[tid];
    float wl  = wl_emb[tid];
    float hp0 = hop_emb[5*256 + tid];
    float hp1 = hop_emb[511*256 + tid];
    float p[6];
    #pragma unroll
    for (int s = 0; s < 6; ++s) p[s] = pos_emb[s*256 + tid];
    #pragma unroll
    for (int r = 0; r < NROW; ++r) {
      int s = r % 6;
      z[r] += br + p[s] + wl + ((s < 2) ? hp0 : hp1);
    }
  }
  ln24_norm(z, redbuf, ln_g[tid], ln_b[tid], tid);
  #pragma unroll
  for (int r = 0; r < NROW; ++r) hs[r][tid] = z[r];

  float resv[NROW];
  #pragma unroll
  for (int r = 0; r < NROW; ++r) resv[r] = 0.f;
  if (bt < 64) {
    __syncthreads();
    for (int idx = tid; idx < TB*6*128; idx += 256) {
      int tt = idx / 768, rem = idx % 768;
      int s = rem >> 7, f = rem & 127;
      int t = bt*TB + tt;
      xbuf[tt*6+s][f] = x[(t*128 + s)*128 + f];
    }
    __syncthreads();
    #pragma unroll 4
    for (int f = 0; f < 128; ++f) {
      float w = W_res[f*256 + tid];
      #pragma unroll
      for (int r = 0; r < NROW; ++r) resv[r] += xbuf[r][f] * w;
    }
    float brr = b_res[tid];
    #pragma unroll
    for (int r = 0; r < NROW; ++r) resv[r] += brr;
  }

  for (int l = 0; l < 4; ++l) {
    const float* Wqkv_l = Wqkv + l*196608;
    const float* bqkv_l = bqkv + l*768;
    const float* Wo_l   = Wo   + l*65536;
    const float* bo_l   = bo   + l*256;
    const float* W1_l   = W1   + l*262144;
    const float* b1_l   = b1   + l*1024;
    const float* W2_l   = W2   + l*262144;
    const float* b2_l   = b2   + l*256;

    __syncthreads();

    for (int cg = 0; cg < 3; ++cg) {
      int col = cg*256 + tid;
      float acc[NROW];
      #pragma unroll
      for (int r = 0; r < NROW; ++r) acc[r] = 0.f;
      #pragma unroll 4
      for (int kk = 0; kk < 256; ++kk) {
        float w = Wqkv_l[kk*768 + col];
        #pragma unroll
        for (int r = 0; r < NROW; ++r) acc[r] += hs[r][kk] * w;
      }
      float bbv = bqkv_l[col];
      #pragma unroll
      for (int r = 0; r < NROW; ++r) qkvs[r][col] = f2bf(acc[r] + bbv);
    }
    __syncthreads();

    #pragma unroll 1
    for (int it = 0; it < 5; ++it) {
      int idx = it*256 + tid;
      if (idx < 1152) {
        int hh = idx / 144, rem = idx % 144;
        int r = rem / 6, sp = rem % 6;
        int tt6 = (r / 6) * 6;
        float sc = 0.f;
        #pragma unroll
        for (int c = 0; c < 32; ++c)
          sc += bf2f(qkvs[r][hh*32 + c]) * bf2f(qkvs[tt6 + sp][256 + hh*32 + c]);
        attw[hh][r][sp] = sc * 0.17677669529663687f;
      }
    }
    __syncthreads();

    if (tid < 192) {
      int hh = tid / 24, r = tid % 24;
      float mx = attw[hh][r][0];
      #pragma unroll
      for (int sp = 1; sp < 6; ++sp) mx = fmaxf(mx, attw[hh][r][sp]);
      float e[6], sum = 0.f;
      #pragma unroll
      for (int sp = 0; sp < 6; ++sp) { e[sp] = expf(attw[hh][r][sp] - mx); sum += e[sp]; }
      float inv = 1.f / sum;
      #pragma unroll
      for (int sp = 0; sp < 6; ++sp) attw[hh][r][sp] = e[sp] * inv;
    }
    __syncthreads();

    float oreg[NROW];
    {
      int hh = tid >> 5, c = tid & 31;
      #pragma unroll
      for (int r = 0; r < NROW; ++r) {
        int tt6 = (r / 6) * 6;
        float o = 0.f;
        #pragma unroll
        for (int sp = 0; sp < 6; ++sp)
          o += attw[hh][r][sp] * bf2f(qkvs[tt6 + sp][512 + hh*32 + c]);
        oreg[r] = o;
      }
    }
    __syncthreads();
    #pragma unroll
    for (int r = 0; r < NROW; ++r) fbuf[r][tid] = oreg[r];
    __syncthreads();

    {
      float bod = bo_l[tid];
      float zz[NROW];
      #pragma unroll
      for (int r = 0; r < NROW; ++r) zz[r] = bod;
      #pragma unroll 4
      for (int kk = 0; kk < 256; ++kk) {
        float w = Wo_l[kk*256 + tid];
        #pragma unroll
        for (int r = 0; r < NROW; ++r) zz[r] += fbuf[r][kk] * w;
      }
      #pragma unroll
      for (int r = 0; r < NROW; ++r) z[r] += zz[r] + resv[r];
    }
    ln24_norm(z, redbuf, n1g[l*256 + tid], n1b[l*256 + tid], tid);
    #pragma unroll
    for (int r = 0; r < NROW; ++r) hs[r][tid] = z[r];
    __syncthreads();

    float ff[NROW];
    {
      float b2d = b2_l[tid];
      #pragma unroll
      for (int r = 0; r < NROW; ++r) ff[r] = b2d;
    }
    for (int ch = 0; ch < 4; ++ch) {
      int j = ch*256 + tid;
      float gvv[NROW];
      float b1j = b1_l[j];
      #pragma unroll
      for (int r = 0; r < NROW; ++r) gvv[r] = b1j;
      #pragma unroll 4
      for (int kk = 0; kk < 256; ++kk) {
        float w = W1_l[kk*1024 + j];
        #pragma unroll
        for (int r = 0; r < NROW; ++r) gvv[r] += hs[r][kk] * w;
      }
      __syncthreads();
      #pragma unroll
      for (int r = 0; r < NROW; ++r) fbuf[r][tid] = gelu_f(gvv[r]);
      __syncthreads();
      #pragma unroll 4
      for (int kk = 0; kk < 256; ++kk) {
        float w = W2_l[(ch*256 + kk)*256 + tid];
        #pragma unroll
        for (int r = 0; r < NROW; ++r) ff[r] += fbuf[r][kk] * w;
      }
    }
    #pragma unroll
    for (int r = 0; r < NROW; ++r) z[r] += ff[r] + resv[r];
    ln24_norm(z, redbuf, n2g[l*256 + tid], n2b[l*256 + tid], tid);
    #pragma unroll
    for (int r = 0; r < NROW; ++r) hs[r][tid] = z[r];
  }

  __syncthreads();
  #pragma unroll
  for (int tt = 0; tt < TB; ++tt)
    out[(bt*TB + tt)*256 + tid] = hs[tt*6][tid];
}

extern "C" void kernel_launch(void* const* d_in, const int* in_sizes, int n_in,
                              void* d_out, int out_size, void* d_ws, size_t ws_size,
                              hipStream_t stream) {
  (void)in_sizes; (void)n_in; (void)out_size;
  const float* x      = (const float*)d_in[0];
  const float* W_raw  = (const float*)d_in[1];
  const float* b_raw  = (const float*)d_in[2];
  const float* wl_emb = (const float*)d_in[3];
  const float* pos_emb= (const float*)d_in[4];
  const float* hop_emb= (const float*)d_in[5];
  const float* ln_g   = (const float*)d_in[6];
  const float* ln_b   = (const float*)d_in[7];
  const float* Wqkv   = (const float*)d_in[8];
  const float* bqkv   = (const float*)d_in[9];
  const float* Wo     = (const float*)d_in[10];
  const float* bo     = (const float*)d_in[11];
  const float* n1g    = (const float*)d_in[12];
  const float* n1b    = (const float*)d_in[13];
  const float* W1     = (const float*)d_in[14];
  const float* b1     = (const float*)d_in[15];
  const float* W2     = (const float*)d_in[16];
  const float* b2     = (const float*)d_in[17];
  const float* n2g    = (const float*)d_in[18];
  const float* n2b    = (const float*)d_in[19];
  const float* W_res  = (const float*)d_in[20];
  const float* b_res  = (const float*)d_in[21];

  if (ws_size >= (size_t)WS_ELEMS * 2) {
    __hip_bfloat16* wsb = (__hip_bfloat16*)d_ws;
    gb_prep_kernel<<<1536, 256, 0, stream>>>(Wqkv, Wo, W1, W2, wsb);
    gb_mfma_kernel<<<8192, 256, 0, stream>>>(
        x, W_raw, b_raw, wl_emb, pos_emb, hop_emb, ln_g, ln_b,
        bqkv, bo, n1g, n1b, b1, b2, n2g, n2b, W_res, b_res,
        wsb, (float*)d_out);
  } else {
    gb_fused_fallback<<<8192, 256, 0, stream>>>(
        x, W_raw, b_raw, wl_emb, pos_emb, hop_emb, ln_g, ln_b,
        Wqkv, bqkv, Wo, bo, n1g, n1b, W1, b1, W2, b2, n2g, n2b,
        W_res, b_res, (float*)d_out);
  }
}